// Round 1
// baseline (519.391 us; speedup 1.0000x reference)
//
#include <hip/hip_runtime.h>
#include <hip/hip_bf16.h>
#include <cstdint>
#include <cstddef>

// ---------------------------------------------------------------------------
// Attention block: qkv = x @ wqkv^T ; rope(q,k) ; causal GQA attention ; out = att @ wo^T
// B=1, S=2048, DIM=4096, NH=32, NKV=8, HD=128. All compute in bf16 MFMA + f32 accum.
// ---------------------------------------------------------------------------

typedef __attribute__((ext_vector_type(4))) float  f32x4;
typedef __attribute__((ext_vector_type(8))) __bf16 bf16x8;
typedef __attribute__((ext_vector_type(4))) __bf16 bf16x4;
typedef __attribute__((ext_vector_type(2))) __bf16 bf16x2;

typedef const __attribute__((address_space(1))) void* gaddr_t;
typedef __attribute__((address_space(3))) void*       laddr_t;

#define S_LEN   2048
#define DIM_    4096
#define NH      32
#define NKV     8
#define HD      128
#define QKV_LD  6144   // row stride of qkv buffer (Q|K|V)
#define KOFF    4096
#define VOFF    5120

// ---------------- f32 -> bf16 conversion (vectorized x4) -------------------
__global__ void cvt_f32_bf16(const float* __restrict__ in, __bf16* __restrict__ out, int n4) {
  int idx = blockIdx.x * blockDim.x + threadIdx.x;
  int stride = gridDim.x * blockDim.x;
  for (int i = idx; i < n4; i += stride) {
    float4 v = reinterpret_cast<const float4*>(in)[i];
    bf16x4 o;
    o[0] = (__bf16)v.x; o[1] = (__bf16)v.y; o[2] = (__bf16)v.z; o[3] = (__bf16)v.w;
    reinterpret_cast<bf16x4*>(out)[i] = o;
  }
}

// ---------------- RoPE in-place on Q and K parts of qkv --------------------
// pairs (2i, 2i+1) within each head dim; 2048 * (32+8) * 64 pairs total.
__global__ void rope_kernel(__bf16* __restrict__ qkv, const float* __restrict__ fc,
                            const float* __restrict__ fs) {
  int tid = blockIdx.x * 256 + threadIdx.x;   // 0 .. 2048*40*64-1
  int i = tid & 63;
  int t = tid >> 6;
  int h = t % 40;
  int s = t / 40;
  int col = (h < NH) ? (h * HD + 2 * i) : (KOFF + (h - NH) * HD + 2 * i);
  size_t off = (size_t)s * QKV_LD + col;
  float c = fc[s * 64 + i], sn = fs[s * 64 + i];
  bf16x2 v = *reinterpret_cast<bf16x2*>(&qkv[off]);
  float t0 = (float)v[0], t1 = (float)v[1];
  bf16x2 o;
  o[0] = (__bf16)(t0 * c - t1 * sn);
  o[1] = (__bf16)(t0 * sn + t1 * c);
  *reinterpret_cast<bf16x2*>(&qkv[off]) = o;
}

// ---------------- GEMM: C[M,N] = A[M,K] * B[N,K]^T (both bf16, row-major) --
// m97 structure: 128x128 tile, BK=32, 4 waves (2x2), 4x4 16x16x32 frags/wave.
template <typename OutT>
__global__ __launch_bounds__(256) void gemm_bt(const __bf16* __restrict__ A,
                                               const __bf16* __restrict__ B,
                                               OutT* __restrict__ C,
                                               int K, int lda, int ldb, int ldc) {
  __shared__ __align__(16) __bf16 As[128 * 32];
  __shared__ __align__(16) __bf16 Bs[128 * 32];
  const int tid = threadIdx.x;
  const int l15 = tid & 15, hi = (tid >> 4) & 3, wid = tid >> 6;
  const int m0 = blockIdx.y * 128, n0 = blockIdx.x * 128;
  const int wr = (wid >> 1) * 64, wc = (wid & 1) * 64;
  f32x4 acc[4][4] = {};
  const int c0 = tid, c1 = tid + 256;

  for (int k0 = 0; k0 < K; k0 += 32) {
    __syncthreads();  // previous iteration's frag reads done
    {
      const __bf16* ga0 = A + (size_t)(m0 + (c0 >> 2)) * lda + k0 + (c0 & 3) * 8;
      const __bf16* ga1 = A + (size_t)(m0 + (c1 >> 2)) * lda + k0 + (c1 & 3) * 8;
      const __bf16* gb0 = B + (size_t)(n0 + (c0 >> 2)) * ldb + k0 + (c0 & 3) * 8;
      const __bf16* gb1 = B + (size_t)(n0 + (c1 >> 2)) * ldb + k0 + (c1 & 3) * 8;
      char* la = (char*)As + (tid & ~63) * 16;
      char* lb = (char*)Bs + (tid & ~63) * 16;
      __builtin_amdgcn_global_load_lds((gaddr_t)ga0, (laddr_t)la, 16, 0, 0);
      __builtin_amdgcn_global_load_lds((gaddr_t)ga1, (laddr_t)(la + 4096), 16, 0, 0);
      __builtin_amdgcn_global_load_lds((gaddr_t)gb0, (laddr_t)lb, 16, 0, 0);
      __builtin_amdgcn_global_load_lds((gaddr_t)gb1, (laddr_t)(lb + 4096), 16, 0, 0);
    }
    __syncthreads();  // staging visible (compiler drains vmcnt before barrier)
    bf16x8 a[4], b[4];
#pragma unroll
    for (int mi = 0; mi < 4; ++mi)
      a[mi] = *reinterpret_cast<const bf16x8*>(&As[(wr + mi * 16 + l15) * 32 + hi * 8]);
#pragma unroll
    for (int ni = 0; ni < 4; ++ni)
      b[ni] = *reinterpret_cast<const bf16x8*>(&Bs[(wc + ni * 16 + l15) * 32 + hi * 8]);
#pragma unroll
    for (int mi = 0; mi < 4; ++mi)
#pragma unroll
      for (int ni = 0; ni < 4; ++ni)
        acc[mi][ni] = __builtin_amdgcn_mfma_f32_16x16x32_bf16(a[mi], b[ni], acc[mi][ni], 0, 0, 0);
  }
  // epilogue: C layout col=lane&15, row=(lane>>4)*4+j
#pragma unroll
  for (int mi = 0; mi < 4; ++mi)
#pragma unroll
    for (int ni = 0; ni < 4; ++ni)
#pragma unroll
      for (int j = 0; j < 4; ++j) {
        int row = m0 + wr + mi * 16 + hi * 4 + j;
        int col = n0 + wc + ni * 16 + l15;
        C[(size_t)row * ldc + col] = (OutT)acc[mi][ni][j];
      }
}

// ---------------- Flash attention, causal, GQA (4 q-heads per kv-head) -----
// grid (S/64, NH); block 256 = 4 waves; wave w owns q rows q0+w*16..+15.
// KV tile = 64 rows. K staged via swizzled-source global_load_lds; V staged
// transposed (reg + ds_write_b32) into padded LDS; P through padded LDS.
__global__ __launch_bounds__(256) void attn_kernel(const __bf16* __restrict__ qkv,
                                                   __bf16* __restrict__ out) {
  __shared__ __align__(16) __bf16 Ks[64 * 128];      // swizzled 16B groups per row
  __shared__ __align__(16) __bf16 Vt[128][72];       // V^T, padded (stride 144B = 9*16)
  __shared__ __align__(16) __bf16 Ps[4][16][72];     // per-wave P, padded
  const int tid = threadIdx.x;
  const int lane = tid & 63, l15 = tid & 15, hi = (tid >> 4) & 3, w = tid >> 6;
  const int bx = blockIdx.x, h = blockIdx.y;
  const int q0 = bx * 64;
  const int kvh = h >> 2;
  const float sc = 0.08838834764831845f;  // 1/sqrt(128)

  // Q fragments (A-layout): lane holds Q[row=l15][k=(hi*8..)+kst*32]
  bf16x8 qf[4];
  {
    const __bf16* qp = qkv + (size_t)(q0 + w * 16 + l15) * QKV_LD + h * HD;
#pragma unroll
    for (int kst = 0; kst < 4; ++kst)
      qf[kst] = *reinterpret_cast<const bf16x8*>(qp + kst * 32 + hi * 8);
  }

  f32x4 o[8] = {};
  float m_run[4], l_run[4];
#pragma unroll
  for (int j = 0; j < 4; ++j) { m_run[j] = -3e38f; l_run[j] = 0.f; }

  for (int jt = 0; jt <= bx; ++jt) {
    const int kv0 = jt * 64;
    __syncthreads();  // previous tile's LDS reads done
    // ---- stage K [64][128] with XOR-swizzled source (2-way banks on read)
#pragma unroll
    for (int i = 0; i < 4; ++i) {
      int c = tid + i * 256;            // 16B chunk id, 0..1023
      int r = c >> 4, g = c & 15;
      const __bf16* gk = qkv + (size_t)(kv0 + r) * QKV_LD + KOFF + kvh * HD + ((g ^ (r & 7)) * 8);
      __builtin_amdgcn_global_load_lds((gaddr_t)gk,
          (laddr_t)((char*)Ks + (tid & ~63) * 16 + i * 4096), 16, 0, 0);
    }
    // ---- stage V^T: thread reads 2 rows x 8 dims, writes 8 packed b32
#pragma unroll
    for (int i = 0; i < 2; ++i) {
      int task = tid + i * 256;         // 0..511
      int p = task >> 4, cg = task & 15;
      const __bf16* vp = qkv + (size_t)(kv0 + 2 * p) * QKV_LD + VOFF + kvh * HD + cg * 8;
      bf16x8 v0 = *reinterpret_cast<const bf16x8*>(vp);
      bf16x8 v1 = *reinterpret_cast<const bf16x8*>(vp + QKV_LD);
#pragma unroll
      for (int e0 = 0; e0 < 8; ++e0) {
        int e = e0 ^ (lane & 7);        // spread banks
        bf16x2 pk; pk[0] = v0[e]; pk[1] = v1[e];
        *reinterpret_cast<bf16x2*>(&Vt[cg * 8 + e][2 * p]) = pk;
      }
    }
    __syncthreads();  // staging visible

    // ---- S = Q K^T (16x64 per wave)
    f32x4 s[4];
#pragma unroll
    for (int nf = 0; nf < 4; ++nf) {
      s[nf] = (f32x4){0.f, 0.f, 0.f, 0.f};
#pragma unroll
      for (int kst = 0; kst < 4; ++kst) {
        int r = nf * 16 + l15;
        int g = (kst * 4 + hi) ^ (r & 7);
        bf16x8 kf = *reinterpret_cast<const bf16x8*>((char*)Ks + r * 256 + g * 16);
        s[nf] = __builtin_amdgcn_mfma_f32_16x16x32_bf16(qf[kst], kf, s[nf], 0, 0, 0);
      }
    }
    // scale + causal mask (diagonal tile only)
#pragma unroll
    for (int nf = 0; nf < 4; ++nf)
#pragma unroll
      for (int jj = 0; jj < 4; ++jj) s[nf][jj] *= sc;
    if (jt == bx) {
#pragma unroll
      for (int nf = 0; nf < 4; ++nf)
#pragma unroll
        for (int jj = 0; jj < 4; ++jj) {
          int rr = w * 16 + hi * 4 + jj;   // q row within block
          int cc = nf * 16 + l15;          // kv col within tile (kv0 == q0)
          if (cc > rr) s[nf][jj] = -1e9f;
        }
    }
    // ---- online softmax
    float pm[4], f[4], rs[4];
#pragma unroll
    for (int jj = 0; jj < 4; ++jj) {
      pm[jj] = fmaxf(fmaxf(s[0][jj], s[1][jj]), fmaxf(s[2][jj], s[3][jj]));
#pragma unroll
      for (int d = 1; d < 16; d <<= 1) pm[jj] = fmaxf(pm[jj], __shfl_xor(pm[jj], d));
      float mn = fmaxf(m_run[jj], pm[jj]);
      f[jj] = __expf(m_run[jj] - mn);
      m_run[jj] = mn;
      rs[jj] = 0.f;
    }
#pragma unroll
    for (int nf = 0; nf < 4; ++nf)
#pragma unroll
      for (int jj = 0; jj < 4; ++jj) {
        float p = __expf(s[nf][jj] - m_run[jj]);
        s[nf][jj] = p;
        rs[jj] += p;
      }
#pragma unroll
    for (int jj = 0; jj < 4; ++jj) {
#pragma unroll
      for (int d = 1; d < 16; d <<= 1) rs[jj] += __shfl_xor(rs[jj], d);
      l_run[jj] = l_run[jj] * f[jj] + rs[jj];
    }
    // rescale O
#pragma unroll
    for (int n8 = 0; n8 < 8; ++n8)
#pragma unroll
      for (int jj = 0; jj < 4; ++jj) o[n8][jj] *= f[jj];
    // ---- P -> LDS (bf16, C-layout scatter)
#pragma unroll
    for (int nf = 0; nf < 4; ++nf)
#pragma unroll
      for (int jj = 0; jj < 4; ++jj)
        Ps[w][hi * 4 + jj][nf * 16 + l15] = (__bf16)s[nf][jj];
    __syncthreads();  // P + V^T visible for all waves

    // ---- O += P V
    bf16x8 pa[2];
#pragma unroll
    for (int kst = 0; kst < 2; ++kst)
      pa[kst] = *reinterpret_cast<const bf16x8*>(&Ps[w][l15][kst * 32 + hi * 8]);
#pragma unroll
    for (int n8 = 0; n8 < 8; ++n8)
#pragma unroll
      for (int kst = 0; kst < 2; ++kst) {
        bf16x8 vb = *reinterpret_cast<const bf16x8*>(&Vt[n8 * 16 + l15][kst * 32 + hi * 8]);
        o[n8] = __builtin_amdgcn_mfma_f32_16x16x32_bf16(pa[kst], vb, o[n8], 0, 0, 0);
      }
  }

  // ---- epilogue: out[row, h*128+col] = o / l
#pragma unroll
  for (int n8 = 0; n8 < 8; ++n8)
#pragma unroll
    for (int jj = 0; jj < 4; ++jj) {
      int row = q0 + w * 16 + hi * 4 + jj;
      int col = h * HD + n8 * 16 + l15;
      out[(size_t)row * DIM_ + col] = (__bf16)(o[n8][jj] / l_run[jj]);
    }
}

// ---------------------------------------------------------------------------
extern "C" void kernel_launch(void* const* d_in, const int* in_sizes, int n_in,
                              void* d_out, int out_size, void* d_ws, size_t ws_size,
                              hipStream_t stream) {
  (void)in_sizes; (void)n_in; (void)out_size; (void)ws_size;
  const float* x    = (const float*)d_in[0];
  const float* fc   = (const float*)d_in[1];
  const float* fs   = (const float*)d_in[2];
  // d_in[3] = mask (causal, hardcoded in attn_kernel)
  const float* wqkv = (const float*)d_in[4];
  const float* wo   = (const float*)d_in[5];
  float* out = (float*)d_out;

  // workspace layout (bytes): total 125,829,120
  char* ws = (char*)d_ws;
  __bf16* xb    = (__bf16*)(ws);                       // 16,777,216  (reused as attn_out)
  __bf16* wqkvb = (__bf16*)(ws + 16777216);            // 50,331,648
  __bf16* wob   = (__bf16*)(ws + 67108864);            // 33,554,432
  __bf16* qkv   = (__bf16*)(ws + 100663296);           // 25,165,824
  __bf16* attnO = xb;                                  // xb dead after gemm1

  cvt_f32_bf16<<<2048, 256, 0, stream>>>(x,    xb,    (S_LEN * DIM_) / 4);
  cvt_f32_bf16<<<2048, 256, 0, stream>>>(wqkv, wqkvb, (6144 * DIM_) / 4);
  cvt_f32_bf16<<<2048, 256, 0, stream>>>(wo,   wob,   (DIM_ * DIM_) / 4);

  // qkv = x @ wqkv^T : M=2048, N=6144, K=4096
  gemm_bt<__bf16><<<dim3(6144 / 128, S_LEN / 128), 256, 0, stream>>>(
      xb, wqkvb, qkv, DIM_, DIM_, DIM_, QKV_LD);

  // rope on Q + K parts
  rope_kernel<<<(S_LEN * 40 * 64) / 256, 256, 0, stream>>>(qkv, fc, fs);

  // causal GQA attention
  attn_kernel<<<dim3(S_LEN / 64, NH), 256, 0, stream>>>(qkv, attnO);

  // out = attnO @ wo^T : M=2048, N=4096, K=4096 (f32 output)
  gemm_bt<float><<<dim3(DIM_ / 128, S_LEN / 128), 256, 0, stream>>>(
      attnO, wob, out, DIM_, DIM_, DIM_, DIM_);
}

// Round 2
// 477.533 us; speedup vs baseline: 1.0877x; 1.0877x over previous
//
#include <hip/hip_runtime.h>
#include <hip/hip_bf16.h>
#include <cstdint>
#include <cstddef>

// ---------------------------------------------------------------------------
// Attention block: qkv = x @ wqkv^T ; rope(q,k) ; causal GQA attention ; out = att @ wo^T
// B=1, S=2048, DIM=4096, NH=32, NKV=8, HD=128. All compute in bf16 MFMA + f32 accum.
// ---------------------------------------------------------------------------

typedef __attribute__((ext_vector_type(4)))  float    f32x4;
typedef __attribute__((ext_vector_type(16))) float    f32x16;
typedef __attribute__((ext_vector_type(8)))  __bf16   bf16x8;
typedef __attribute__((ext_vector_type(4)))  __bf16   bf16x4;
typedef __attribute__((ext_vector_type(2)))  __bf16   bf16x2;
typedef __attribute__((ext_vector_type(4)))  uint32_t u32x4;

typedef const __attribute__((address_space(1))) void* gaddr_t;
typedef __attribute__((address_space(3))) void*       laddr_t;

#define S_LEN   2048
#define DIM_    4096
#define NH      32
#define NKV     8
#define HD      128
#define QKV_LD  6144   // row stride of qkv buffer (Q|K|V)
#define KOFF    4096
#define VOFF    5120

// ---------------- f32 -> bf16 conversion (vectorized x4) -------------------
__global__ void cvt_f32_bf16(const float* __restrict__ in, __bf16* __restrict__ out, int n4) {
  int idx = blockIdx.x * blockDim.x + threadIdx.x;
  int stride = gridDim.x * blockDim.x;
  for (int i = idx; i < n4; i += stride) {
    float4 v = reinterpret_cast<const float4*>(in)[i];
    bf16x4 o;
    o[0] = (__bf16)v.x; o[1] = (__bf16)v.y; o[2] = (__bf16)v.z; o[3] = (__bf16)v.w;
    reinterpret_cast<bf16x4*>(out)[i] = o;
  }
}

// ---------------- RoPE in-place on Q and K parts of qkv --------------------
__global__ void rope_kernel(__bf16* __restrict__ qkv, const float* __restrict__ fc,
                            const float* __restrict__ fs) {
  int tid = blockIdx.x * 256 + threadIdx.x;   // 0 .. 2048*40*64-1
  int i = tid & 63;
  int t = tid >> 6;
  int h = t % 40;
  int s = t / 40;
  int col = (h < NH) ? (h * HD + 2 * i) : (KOFF + (h - NH) * HD + 2 * i);
  size_t off = (size_t)s * QKV_LD + col;
  float c = fc[s * 64 + i], sn = fs[s * 64 + i];
  bf16x2 v = *reinterpret_cast<bf16x2*>(&qkv[off]);
  float t0 = (float)v[0], t1 = (float)v[1];
  bf16x2 o;
  o[0] = (__bf16)(t0 * c - t1 * sn);
  o[1] = (__bf16)(t0 * sn + t1 * c);
  *reinterpret_cast<bf16x2*>(&qkv[off]) = o;
}

// ---------------- GEMM: C[M,N] = A[M,K] * B[N,K]^T (both bf16, row-major) --
template <typename OutT>
__global__ __launch_bounds__(256) void gemm_bt(const __bf16* __restrict__ A,
                                               const __bf16* __restrict__ B,
                                               OutT* __restrict__ C,
                                               int K, int lda, int ldb, int ldc) {
  __shared__ __align__(16) __bf16 As[128 * 32];
  __shared__ __align__(16) __bf16 Bs[128 * 32];
  const int tid = threadIdx.x;
  const int l15 = tid & 15, hi = (tid >> 4) & 3, wid = tid >> 6;
  const int m0 = blockIdx.y * 128, n0 = blockIdx.x * 128;
  const int wr = (wid >> 1) * 64, wc = (wid & 1) * 64;
  f32x4 acc[4][4] = {};
  const int c0 = tid, c1 = tid + 256;

  for (int k0 = 0; k0 < K; k0 += 32) {
    __syncthreads();
    {
      const __bf16* ga0 = A + (size_t)(m0 + (c0 >> 2)) * lda + k0 + (c0 & 3) * 8;
      const __bf16* ga1 = A + (size_t)(m0 + (c1 >> 2)) * lda + k0 + (c1 & 3) * 8;
      const __bf16* gb0 = B + (size_t)(n0 + (c0 >> 2)) * ldb + k0 + (c0 & 3) * 8;
      const __bf16* gb1 = B + (size_t)(n0 + (c1 >> 2)) * ldb + k0 + (c1 & 3) * 8;
      char* la = (char*)As + (tid & ~63) * 16;
      char* lb = (char*)Bs + (tid & ~63) * 16;
      __builtin_amdgcn_global_load_lds((gaddr_t)ga0, (laddr_t)la, 16, 0, 0);
      __builtin_amdgcn_global_load_lds((gaddr_t)ga1, (laddr_t)(la + 4096), 16, 0, 0);
      __builtin_amdgcn_global_load_lds((gaddr_t)gb0, (laddr_t)lb, 16, 0, 0);
      __builtin_amdgcn_global_load_lds((gaddr_t)gb1, (laddr_t)(lb + 4096), 16, 0, 0);
    }
    __syncthreads();
    bf16x8 a[4], b[4];
#pragma unroll
    for (int mi = 0; mi < 4; ++mi)
      a[mi] = *reinterpret_cast<const bf16x8*>(&As[(wr + mi * 16 + l15) * 32 + hi * 8]);
#pragma unroll
    for (int ni = 0; ni < 4; ++ni)
      b[ni] = *reinterpret_cast<const bf16x8*>(&Bs[(wc + ni * 16 + l15) * 32 + hi * 8]);
#pragma unroll
    for (int mi = 0; mi < 4; ++mi)
#pragma unroll
      for (int ni = 0; ni < 4; ++ni)
        acc[mi][ni] = __builtin_amdgcn_mfma_f32_16x16x32_bf16(a[mi], b[ni], acc[mi][ni], 0, 0, 0);
  }
#pragma unroll
  for (int mi = 0; mi < 4; ++mi)
#pragma unroll
    for (int ni = 0; ni < 4; ++ni)
#pragma unroll
      for (int j = 0; j < 4; ++j) {
        int row = m0 + wr + mi * 16 + hi * 4 + j;
        int col = n0 + wc + ni * 16 + l15;
        C[(size_t)row * ldc + col] = (OutT)acc[mi][ni][j];
      }
}

// ---------------- Flash attention, causal, GQA — 32x32 swapped structure ---
// grid 1024 blocks x 128 thr (2 waves). Block = (head, q-tile of 64 rows),
// qt scrambled vs blockIdx for load balance. Wave wq owns 32 q rows; lane
// owns ONE q row (col of S^T). Softmax lane-local; P packed in-register.
__device__ inline uint32_t pack2(float a, float b) {
  bf16x2 t; t[0] = (__bf16)a; t[1] = (__bf16)b;
  return __builtin_bit_cast(uint32_t, t);
}

__global__ __launch_bounds__(128, 2) void attn_kernel(const __bf16* __restrict__ qkv,
                                                      __bf16* __restrict__ out) {
  __shared__ __align__(16) __bf16 Ks[64 * 128];   // XOR-swizzled 16B groups per row
  __shared__ __align__(16) __bf16 Vt[128][72];    // V^T, padded (stride 144B)
  const int tid = threadIdx.x;
  const int lane = tid & 63, l31 = lane & 31, hi = lane >> 5, wq = tid >> 6;
  const int b = blockIdx.x;
  const int head = b >> 5;
  const int qt = ((b & 31) + head) & 31;          // balance: resident sets get qt spread
  const int q0 = qt * 64;
  const int kvh = head >> 2;
  const float sc = 0.08838834764831845f;          // 1/sqrt(128)
  const int qr = q0 + wq * 32 + l31;              // this lane's q row

  // Q fragments (B-layout): lane holds Q[qr][k = ks*16 + hi*8 + 0..7]
  bf16x8 qf[8];
  {
    const __bf16* qp = qkv + (size_t)qr * QKV_LD + head * HD + hi * 8;
#pragma unroll
    for (int ks = 0; ks < 8; ++ks) qf[ks] = *reinterpret_cast<const bf16x8*>(qp + ks * 16);
  }

  f32x16 o[4] = {};                               // O^T[dtile][rowmap][q=l31]
  float m_run = -3e38f, l_run = 0.f;

  for (int jt = 0; jt <= qt; ++jt) {
    const int kv0 = jt * 64;
    __syncthreads();  // prev tile's LDS reads done
    // ---- stage K [64][128], XOR-swizzled source -> linear LDS
#pragma unroll
    for (int i = 0; i < 8; ++i) {
      int c = i * 128 + tid;            // 16B chunk id 0..1023
      int r = c >> 4, g = c & 15;
      const __bf16* gk = qkv + (size_t)(kv0 + r) * QKV_LD + KOFF + kvh * HD + ((g ^ (r & 7)) * 8);
      __builtin_amdgcn_global_load_lds((gaddr_t)gk,
          (laddr_t)((char*)Ks + (tid & ~63) * 16 + i * 2048), 16, 0, 0);
    }
    // ---- stage V^T (reg transpose, 2 rows x 8 dims per task)
#pragma unroll
    for (int i = 0; i < 4; ++i) {
      int task = i * 128 + tid;         // 0..511
      int p = task >> 4, cg = task & 15;
      const __bf16* vp = qkv + (size_t)(kv0 + 2 * p) * QKV_LD + VOFF + kvh * HD + cg * 8;
      bf16x8 v0 = *reinterpret_cast<const bf16x8*>(vp);
      bf16x8 v1 = *reinterpret_cast<const bf16x8*>(vp + QKV_LD);
#pragma unroll
      for (int e0 = 0; e0 < 8; ++e0) {
        int e = e0 ^ (lane & 7);
        bf16x2 pkv; pkv[0] = v0[e]; pkv[1] = v1[e];
        *reinterpret_cast<bf16x2*>(&Vt[cg * 8 + e][2 * p]) = pkv;
      }
    }
    __syncthreads();  // staging visible

    // ---- S^T = K Q^T : D[kv][q], col=q=lane&31, row=(e&3)+8*(e>>2)+4*hi
    f32x16 st[2];
#pragma unroll
    for (int sub = 0; sub < 2; ++sub) {
      f32x16 acc = {};
      int r = sub * 32 + l31;
#pragma unroll
      for (int ks = 0; ks < 8; ++ks) {
        int g = (ks * 2 + hi) ^ (r & 7);
        bf16x8 kf = *reinterpret_cast<const bf16x8*>((char*)Ks + r * 256 + g * 16);
        acc = __builtin_amdgcn_mfma_f32_32x32x16_bf16(kf, qf[ks], acc, 0, 0, 0);
      }
      st[sub] = acc;
    }
    // ---- scale + causal mask (diagonal tile only)
#pragma unroll
    for (int sub = 0; sub < 2; ++sub)
#pragma unroll
      for (int e = 0; e < 16; ++e) st[sub][e] *= sc;
    if (jt == qt) {
#pragma unroll
      for (int sub = 0; sub < 2; ++sub)
#pragma unroll
        for (int e = 0; e < 16; ++e) {
          int kvg = kv0 + sub * 32 + (e & 3) + 8 * (e >> 2) + 4 * hi;
          if (kvg > qr) st[sub][e] = -1e30f;
        }
    }
    // ---- online softmax (lane-local + one cross-half swap)
    float pm = st[0][0];
#pragma unroll
    for (int e = 1; e < 16; ++e) pm = fmaxf(pm, st[0][e]);
#pragma unroll
    for (int e = 0; e < 16; ++e) pm = fmaxf(pm, st[1][e]);
    pm = fmaxf(pm, __shfl_xor(pm, 32));
    float mn = fmaxf(m_run, pm);
    float fs = __expf(m_run - mn);
    m_run = mn;
    float rs = 0.f;
#pragma unroll
    for (int sub = 0; sub < 2; ++sub)
#pragma unroll
      for (int e = 0; e < 16; ++e) {
        float p = __expf(st[sub][e] - mn);
        st[sub][e] = p;
        rs += p;
      }
    rs += __shfl_xor(rs, 32);
    l_run = l_run * fs + rs;
#pragma unroll
    for (int dt = 0; dt < 4; ++dt)
#pragma unroll
      for (int e = 0; e < 16; ++e) o[dt][e] *= fs;

    // ---- pack P to bf16 B-fragments: pf[t] = P[qr][kv = t*16 + hi*8 + 0..7]
    uint32_t pk[16];
#pragma unroll
    for (int sub = 0; sub < 2; ++sub)
#pragma unroll
      for (int i = 0; i < 8; ++i)
        pk[sub * 8 + i] = pack2(st[sub][2 * i], st[sub][2 * i + 1]);
    uint32_t rv[8];
#pragma unroll
    for (int m = 0; m < 8; ++m) {
      int base = 4 * (m >> 1) + (m & 1);
      uint32_t snd = hi ? pk[base] : pk[base + 2];
      rv[m] = __shfl_xor(snd, 32);
    }
    bf16x8 pf[4];
#pragma unroll
    for (int t = 0; t < 4; ++t) {
      u32x4 w;
      w[0] = hi ? rv[2 * t]     : pk[4 * t];
      w[1] = hi ? rv[2 * t + 1] : pk[4 * t + 1];
      w[2] = hi ? pk[4 * t + 2] : rv[2 * t];
      w[3] = hi ? pk[4 * t + 3] : rv[2 * t + 1];
      pf[t] = __builtin_bit_cast(bf16x8, w);
    }
    // ---- O^T += V^T P^T
#pragma unroll
    for (int dt = 0; dt < 4; ++dt) {
      int dr = dt * 32 + l31;
#pragma unroll
      for (int t = 0; t < 4; ++t) {
        bf16x8 vf = *reinterpret_cast<const bf16x8*>((char*)&Vt[0][0] + dr * 144 + t * 32 + hi * 16);
        o[dt] = __builtin_amdgcn_mfma_f32_32x32x16_bf16(vf, pf[t], o[dt], 0, 0, 0);
      }
    }
  }

  // ---- epilogue: transpose O^T -> O through per-wave LDS scratch, coalesced stores
  float inv = 1.f / l_run;
  __bf16* scr = Ks + wq * 1280;                   // [32][40] bf16 per wave
  const int qq = lane >> 1, part = lane & 1;
#pragma unroll
  for (int dt = 0; dt < 4; ++dt) {
    __syncthreads();                              // prev reads (Ks / prev dt) done
#pragma unroll
    for (int i = 0; i < 8; ++i) {
      int d0 = (2 * i & 3) + 8 * (i >> 1) + 4 * hi;
      bf16x2 pr;
      pr[0] = (__bf16)(o[dt][2 * i] * inv);
      pr[1] = (__bf16)(o[dt][2 * i + 1] * inv);
      *reinterpret_cast<bf16x2*>(scr + l31 * 40 + d0) = pr;
    }
    __syncthreads();
    bf16x8 r0 = *reinterpret_cast<const bf16x8*>(scr + qq * 40 + part * 16);
    bf16x8 r1 = *reinterpret_cast<const bf16x8*>(scr + qq * 40 + part * 16 + 8);
    __bf16* op = out + (size_t)(q0 + wq * 32 + qq) * DIM_ + head * HD + dt * 32 + part * 16;
    *reinterpret_cast<bf16x8*>(op) = r0;
    *reinterpret_cast<bf16x8*>(op + 8) = r1;
  }
}

// ---------------------------------------------------------------------------
extern "C" void kernel_launch(void* const* d_in, const int* in_sizes, int n_in,
                              void* d_out, int out_size, void* d_ws, size_t ws_size,
                              hipStream_t stream) {
  (void)in_sizes; (void)n_in; (void)out_size; (void)ws_size;
  const float* x    = (const float*)d_in[0];
  const float* fc   = (const float*)d_in[1];
  const float* fs   = (const float*)d_in[2];
  // d_in[3] = mask (causal, hardcoded in attn_kernel)
  const float* wqkv = (const float*)d_in[4];
  const float* wo   = (const float*)d_in[5];
  float* out = (float*)d_out;

  char* ws = (char*)d_ws;
  __bf16* xb    = (__bf16*)(ws);                       // 16,777,216  (reused as attn_out)
  __bf16* wqkvb = (__bf16*)(ws + 16777216);            // 50,331,648
  __bf16* wob   = (__bf16*)(ws + 67108864);            // 33,554,432
  __bf16* qkv   = (__bf16*)(ws + 100663296);           // 25,165,824
  __bf16* attnO = xb;                                  // xb dead after gemm1

  cvt_f32_bf16<<<2048, 256, 0, stream>>>(x,    xb,    (S_LEN * DIM_) / 4);
  cvt_f32_bf16<<<2048, 256, 0, stream>>>(wqkv, wqkvb, (6144 * DIM_) / 4);
  cvt_f32_bf16<<<2048, 256, 0, stream>>>(wo,   wob,   (DIM_ * DIM_) / 4);

  // qkv = x @ wqkv^T : M=2048, N=6144, K=4096
  gemm_bt<__bf16><<<dim3(6144 / 128, S_LEN / 128), 256, 0, stream>>>(
      xb, wqkvb, qkv, DIM_, DIM_, DIM_, QKV_LD);

  // rope on Q + K parts
  rope_kernel<<<(S_LEN * 40 * 64) / 256, 256, 0, stream>>>(qkv, fc, fs);

  // causal GQA attention (1024 blocks x 128 threads)
  attn_kernel<<<1024, 128, 0, stream>>>(qkv, attnO);

  // out = attnO @ wo^T : M=2048, N=4096, K=4096 (f32 output)
  gemm_bt<float><<<dim3(DIM_ / 128, S_LEN / 128), 256, 0, stream>>>(
      attnO, wob, out, DIM_, DIM_, DIM_, DIM_);
}

// Round 4
// 405.461 us; speedup vs baseline: 1.2810x; 1.1778x over previous
//
#include <hip/hip_runtime.h>
#include <hip/hip_bf16.h>
#include <cstdint>
#include <cstddef>

// ---------------------------------------------------------------------------
// Attention block: qkv = x @ wqkv^T ; rope(q,k) ; causal GQA attention ; out = att @ wo^T
// B=1, S=2048, DIM=4096, NH=32, NKV=8, HD=128. All compute in bf16 MFMA + f32 accum.
// ---------------------------------------------------------------------------

typedef __attribute__((ext_vector_type(4)))  float    f32x4;
typedef __attribute__((ext_vector_type(16))) float    f32x16;
typedef __attribute__((ext_vector_type(8)))  __bf16   bf16x8;
typedef __attribute__((ext_vector_type(4)))  __bf16   bf16x4;
typedef __attribute__((ext_vector_type(2)))  __bf16   bf16x2;
typedef __attribute__((ext_vector_type(4)))  uint32_t u32x4;

typedef const __attribute__((address_space(1))) void* gaddr_t;
typedef __attribute__((address_space(3))) void*       laddr_t;

#define S_LEN   2048
#define DIM_    4096
#define NH      32
#define NKV     8
#define HD      128
#define QKV_LD  6144   // row stride of qkv buffer (Q|K|V)
#define KOFF    4096
#define VOFF    5120

#define EXP2F(x) __builtin_amdgcn_exp2f(x)   // v_exp_f32 (2^x); __exp2f collides with glibc macro

// ---------------- f32 -> bf16 conversion (vectorized x4) -------------------
__global__ void cvt_f32_bf16(const float* __restrict__ in, __bf16* __restrict__ out, int n4) {
  int idx = blockIdx.x * blockDim.x + threadIdx.x;
  int stride = gridDim.x * blockDim.x;
  for (int i = idx; i < n4; i += stride) {
    float4 v = reinterpret_cast<const float4*>(in)[i];
    bf16x4 o;
    o[0] = (__bf16)v.x; o[1] = (__bf16)v.y; o[2] = (__bf16)v.z; o[3] = (__bf16)v.w;
    reinterpret_cast<bf16x4*>(out)[i] = o;
  }
}

// ---------------- RoPE in-place on Q and K parts of qkv --------------------
__global__ void rope_kernel(__bf16* __restrict__ qkv, const float* __restrict__ fc,
                            const float* __restrict__ fs) {
  int tid = blockIdx.x * 256 + threadIdx.x;   // 0 .. 2048*40*64-1
  int i = tid & 63;
  int t = tid >> 6;
  int h = t % 40;
  int s = t / 40;
  int col = (h < NH) ? (h * HD + 2 * i) : (KOFF + (h - NH) * HD + 2 * i);
  size_t off = (size_t)s * QKV_LD + col;
  float c = fc[s * 64 + i], sn = fs[s * 64 + i];
  bf16x2 v = *reinterpret_cast<bf16x2*>(&qkv[off]);
  float t0 = (float)v[0], t1 = (float)v[1];
  bf16x2 o;
  o[0] = (__bf16)(t0 * c - t1 * sn);
  o[1] = (__bf16)(t0 * sn + t1 * c);
  *reinterpret_cast<bf16x2*>(&qkv[off]) = o;
}

// ---------------- GEMM: C[M,N] = A[M,K] * B[N,K]^T (both bf16, row-major) --
template <typename OutT>
__global__ __launch_bounds__(256) void gemm_bt(const __bf16* __restrict__ A,
                                               const __bf16* __restrict__ B,
                                               OutT* __restrict__ C,
                                               int K, int lda, int ldb, int ldc) {
  __shared__ __align__(16) __bf16 As[128 * 32];
  __shared__ __align__(16) __bf16 Bs[128 * 32];
  const int tid = threadIdx.x;
  const int l15 = tid & 15, hi = (tid >> 4) & 3, wid = tid >> 6;
  const int m0 = blockIdx.y * 128, n0 = blockIdx.x * 128;
  const int wr = (wid >> 1) * 64, wc = (wid & 1) * 64;
  f32x4 acc[4][4] = {};
  const int c0 = tid, c1 = tid + 256;

  for (int k0 = 0; k0 < K; k0 += 32) {
    __syncthreads();
    {
      const __bf16* ga0 = A + (size_t)(m0 + (c0 >> 2)) * lda + k0 + (c0 & 3) * 8;
      const __bf16* ga1 = A + (size_t)(m0 + (c1 >> 2)) * lda + k0 + (c1 & 3) * 8;
      const __bf16* gb0 = B + (size_t)(n0 + (c0 >> 2)) * ldb + k0 + (c0 & 3) * 8;
      const __bf16* gb1 = B + (size_t)(n0 + (c1 >> 2)) * ldb + k0 + (c1 & 3) * 8;
      char* la = (char*)As + (tid & ~63) * 16;
      char* lb = (char*)Bs + (tid & ~63) * 16;
      __builtin_amdgcn_global_load_lds((gaddr_t)ga0, (laddr_t)la, 16, 0, 0);
      __builtin_amdgcn_global_load_lds((gaddr_t)ga1, (laddr_t)(la + 4096), 16, 0, 0);
      __builtin_amdgcn_global_load_lds((gaddr_t)gb0, (laddr_t)lb, 16, 0, 0);
      __builtin_amdgcn_global_load_lds((gaddr_t)gb1, (laddr_t)(lb + 4096), 16, 0, 0);
    }
    __syncthreads();
    bf16x8 a[4], b[4];
#pragma unroll
    for (int mi = 0; mi < 4; ++mi)
      a[mi] = *reinterpret_cast<const bf16x8*>(&As[(wr + mi * 16 + l15) * 32 + hi * 8]);
#pragma unroll
    for (int ni = 0; ni < 4; ++ni)
      b[ni] = *reinterpret_cast<const bf16x8*>(&Bs[(wc + ni * 16 + l15) * 32 + hi * 8]);
#pragma unroll
    for (int mi = 0; mi < 4; ++mi)
#pragma unroll
      for (int ni = 0; ni < 4; ++ni)
        acc[mi][ni] = __builtin_amdgcn_mfma_f32_16x16x32_bf16(a[mi], b[ni], acc[mi][ni], 0, 0, 0);
  }
#pragma unroll
  for (int mi = 0; mi < 4; ++mi)
#pragma unroll
    for (int ni = 0; ni < 4; ++ni)
#pragma unroll
      for (int j = 0; j < 4; ++j) {
        int row = m0 + wr + mi * 16 + hi * 4 + j;
        int col = n0 + wc + ni * 16 + l15;
        C[(size_t)row * ldc + col] = (OutT)acc[mi][ni][j];
      }
}

// ---------------- Flash attention, causal, GQA — balanced + pipelined ------
// 256 blocks x 256 thr (4 waves x 32 q-rows = QBLK 128). Block = (head, pair):
// processes q-tiles qt=pr and qt=15-pr sequentially -> EVERY block = 34
// kv-tile iterations (perfect balance, 1 block/CU). K and V^T double-buffered;
// one barrier per tile; staging for t+1 issued at top of t (latency hidden).
__device__ inline uint32_t pack2(float a, float b) {
  bf16x2 t; t[0] = (__bf16)a; t[1] = (__bf16)b;
  return __builtin_bit_cast(uint32_t, t);
}

__global__ __launch_bounds__(256, 2) void attn_kernel(const __bf16* __restrict__ qkv,
                                                      __bf16* __restrict__ out) {
  __shared__ __align__(16) __bf16 Ks[2][64 * 128];   // XOR-swizzled 16B groups
  __shared__ __align__(16) __bf16 Vt[2][128][72];    // V^T, padded (stride 144B)
  const int tid = threadIdx.x;
  const int lane = tid & 63, l31 = lane & 31, hi = lane >> 5, wq = tid >> 6;
  const int head = blockIdx.x & 31;
  const int pr = blockIdx.x >> 5;                    // 0..7
  const int kvh = head >> 2;
  const float sc2 = 0.08838834764831845f * 1.44269504089f;  // 1/sqrt(128)*log2(e)

  bf16x8 vr[2][2];  // in-flight V rows (2 tasks x 2 rows)

  auto stage_k = [&](int tt, int buf) {
#pragma unroll
    for (int i = 0; i < 4; ++i) {
      int c = i * 256 + tid;                         // 16B chunk 0..1023
      int r = c >> 4, g = c & 15;
      const __bf16* gk = qkv + (size_t)(tt * 64 + r) * QKV_LD + KOFF + kvh * HD + ((g ^ (r & 7)) * 8);
      __builtin_amdgcn_global_load_lds((gaddr_t)gk,
          (laddr_t)((char*)Ks[buf] + (tid & ~63) * 16 + i * 4096), 16, 0, 0);
    }
  };
  auto load_v = [&](int tt) {
#pragma unroll
    for (int i = 0; i < 2; ++i) {
      int task = i * 256 + tid;                      // 0..511
      int p = task >> 4, cg = task & 15;
      const __bf16* vp = qkv + (size_t)(tt * 64 + 2 * p) * QKV_LD + VOFF + kvh * HD + cg * 8;
      vr[i][0] = *reinterpret_cast<const bf16x8*>(vp);
      vr[i][1] = *reinterpret_cast<const bf16x8*>(vp + QKV_LD);
    }
  };
  auto write_v = [&](int buf) {
#pragma unroll
    for (int i = 0; i < 2; ++i) {
      int task = i * 256 + tid;
      int p = task >> 4, cg = task & 15;
#pragma unroll
      for (int e0 = 0; e0 < 8; ++e0) {
        int e = e0 ^ (lane & 7);
        bf16x2 pkv; pkv[0] = vr[i][0][e]; pkv[1] = vr[i][1][e];
        *reinterpret_cast<bf16x2*>(&Vt[buf][cg * 8 + e][2 * p]) = pkv;
      }
    }
  };

  for (int pass = 0; pass < 2; ++pass) {
    const int qt = pass ? (15 - pr) : pr;
    const int q0 = qt * 128;
    const int nt = 2 * qt + 2;                       // kv tiles (causal)
    const int qr = q0 + wq * 32 + l31;               // this lane's q row

    // Q fragments (B-layout): lane holds Q[qr][k = ks*16 + hi*8 + 0..7]
    bf16x8 qf[8];
    {
      const __bf16* qp = qkv + (size_t)qr * QKV_LD + head * HD + hi * 8;
#pragma unroll
      for (int ks = 0; ks < 8; ++ks) qf[ks] = *reinterpret_cast<const bf16x8*>(qp + ks * 16);
    }
    f32x16 o[4] = {};
    float m_run = -3e38f, l_run = 0.f;

    __syncthreads();          // prev pass epilogue LDS reads done (no-op cost pass 0)
    stage_k(0, 0); load_v(0); write_v(0);

    for (int t = 0; t < nt; ++t) {
      const int cur = t & 1;
      __syncthreads();        // staging of buf[cur] visible; prev reads of buf[1-cur] done
      if (t + 1 < nt) { stage_k(t + 1, 1 - cur); load_v(t + 1); }

      // ---- S^T = K Q^T : col=q=l31, row=(e&3)+8*(e>>2)+4*hi
      f32x16 st[2];
#pragma unroll
      for (int sub = 0; sub < 2; ++sub) {
        f32x16 acc = {};
        int r = sub * 32 + l31;
#pragma unroll
        for (int ks = 0; ks < 8; ++ks) {
          int g = (ks * 2 + hi) ^ (r & 7);
          bf16x8 kf = *reinterpret_cast<const bf16x8*>((char*)Ks[cur] + r * 256 + g * 16);
          acc = __builtin_amdgcn_mfma_f32_32x32x16_bf16(kf, qf[ks], acc, 0, 0, 0);
        }
        st[sub] = acc;
      }
#pragma unroll
      for (int sub = 0; sub < 2; ++sub)
#pragma unroll
        for (int e = 0; e < 16; ++e) st[sub][e] *= sc2;
      if (t >= nt - 2) {      // only the two diagonal tiles need masking
        const int kv0 = t * 64;
#pragma unroll
        for (int sub = 0; sub < 2; ++sub)
#pragma unroll
          for (int e = 0; e < 16; ++e) {
            int kvg = kv0 + sub * 32 + (e & 3) + 8 * (e >> 2) + 4 * hi;
            if (kvg > qr) st[sub][e] = -1e30f;
          }
      }
      // ---- online softmax (lane-local, defer-max)
      float pm = st[0][0];
#pragma unroll
      for (int e = 1; e < 16; ++e) pm = fmaxf(pm, st[0][e]);
#pragma unroll
      for (int e = 0; e < 16; ++e) pm = fmaxf(pm, st[1][e]);
      pm = fmaxf(pm, __shfl_xor(pm, 32));
      if (!__all(pm - m_run <= 8.f)) {
        float mn = fmaxf(m_run, pm);
        float fsc = EXP2F(m_run - mn);
        m_run = mn;
        l_run *= fsc;
#pragma unroll
        for (int dt = 0; dt < 4; ++dt)
#pragma unroll
          for (int e = 0; e < 16; ++e) o[dt][e] *= fsc;
      }
      float rs = 0.f;
#pragma unroll
      for (int sub = 0; sub < 2; ++sub)
#pragma unroll
        for (int e = 0; e < 16; ++e) {
          float p = EXP2F(st[sub][e] - m_run);
          st[sub][e] = p;
          rs += p;
        }
      rs += __shfl_xor(rs, 32);
      l_run += rs;

      // ---- pack P to bf16 B-fragments: pf[tt] = P[qr][kv = tt*16 + hi*8 + 0..7]
      uint32_t pk[16];
#pragma unroll
      for (int sub = 0; sub < 2; ++sub)
#pragma unroll
        for (int i = 0; i < 8; ++i)
          pk[sub * 8 + i] = pack2(st[sub][2 * i], st[sub][2 * i + 1]);
      uint32_t rv[8];
#pragma unroll
      for (int m = 0; m < 8; ++m) {
        int base = 4 * (m >> 1) + (m & 1);
        uint32_t snd = hi ? pk[base] : pk[base + 2];
        rv[m] = __shfl_xor(snd, 32);
      }
      bf16x8 pf[4];
#pragma unroll
      for (int tt = 0; tt < 4; ++tt) {
        u32x4 w;
        w[0] = hi ? rv[2 * tt]     : pk[4 * tt];
        w[1] = hi ? rv[2 * tt + 1] : pk[4 * tt + 1];
        w[2] = hi ? pk[4 * tt + 2] : rv[2 * tt];
        w[3] = hi ? pk[4 * tt + 3] : rv[2 * tt + 1];
        pf[tt] = __builtin_bit_cast(bf16x8, w);
      }
      // ---- O^T += V^T P^T
#pragma unroll
      for (int dt = 0; dt < 4; ++dt) {
        int dr = dt * 32 + l31;
#pragma unroll
        for (int tt = 0; tt < 4; ++tt) {
          bf16x8 vf = *reinterpret_cast<const bf16x8*>((char*)&Vt[cur][0][0] + dr * 144 + tt * 32 + hi * 16);
          o[dt] = __builtin_amdgcn_mfma_f32_32x32x16_bf16(vf, pf[tt], o[dt], 0, 0, 0);
        }
      }
      // ---- late V^T write for next tile (loads had QK+softmax+PV to land)
      if (t + 1 < nt) write_v(1 - cur);
    }

    // ---- epilogue: transpose O^T -> O via per-wave LDS scratch, coalesced stores
    float inv = 1.f / l_run;
    __bf16* scr = &Ks[0][0] + wq * 1280;             // [32][40] bf16 per wave
    const int qq = lane >> 1, part = lane & 1;
#pragma unroll
    for (int dt = 0; dt < 4; ++dt) {
      __syncthreads();                               // all waves done reading Ks/Vt (or prev dt)
#pragma unroll
      for (int i = 0; i < 8; ++i) {
        int d0 = (2 * i & 3) + 8 * (i >> 1) + 4 * hi;
        bf16x2 prr;
        prr[0] = (__bf16)(o[dt][2 * i] * inv);
        prr[1] = (__bf16)(o[dt][2 * i + 1] * inv);
        *reinterpret_cast<bf16x2*>(scr + l31 * 40 + d0) = prr;
      }
      __syncthreads();
      bf16x8 r0 = *reinterpret_cast<const bf16x8*>(scr + qq * 40 + part * 16);
      bf16x8 r1 = *reinterpret_cast<const bf16x8*>(scr + qq * 40 + part * 16 + 8);
      __bf16* op = out + (size_t)(q0 + wq * 32 + qq) * DIM_ + head * HD + dt * 32 + part * 16;
      *reinterpret_cast<bf16x8*>(op) = r0;
      *reinterpret_cast<bf16x8*>(op + 8) = r1;
    }
  }
}

// ---------------------------------------------------------------------------
extern "C" void kernel_launch(void* const* d_in, const int* in_sizes, int n_in,
                              void* d_out, int out_size, void* d_ws, size_t ws_size,
                              hipStream_t stream) {
  (void)in_sizes; (void)n_in; (void)out_size; (void)ws_size;
  const float* x    = (const float*)d_in[0];
  const float* fc   = (const float*)d_in[1];
  const float* fs   = (const float*)d_in[2];
  // d_in[3] = mask (causal, hardcoded in attn_kernel)
  const float* wqkv = (const float*)d_in[4];
  const float* wo   = (const float*)d_in[5];
  float* out = (float*)d_out;

  char* ws = (char*)d_ws;
  __bf16* xb    = (__bf16*)(ws);                       // 16,777,216  (reused as attn_out)
  __bf16* wqkvb = (__bf16*)(ws + 16777216);            // 50,331,648
  __bf16* wob   = (__bf16*)(ws + 67108864);            // 33,554,432
  __bf16* qkv   = (__bf16*)(ws + 100663296);           // 25,165,824
  __bf16* attnO = xb;                                  // xb dead after gemm1

  cvt_f32_bf16<<<2048, 256, 0, stream>>>(x,    xb,    (S_LEN * DIM_) / 4);
  cvt_f32_bf16<<<2048, 256, 0, stream>>>(wqkv, wqkvb, (6144 * DIM_) / 4);
  cvt_f32_bf16<<<2048, 256, 0, stream>>>(wo,   wob,   (DIM_ * DIM_) / 4);

  // qkv = x @ wqkv^T : M=2048, N=6144, K=4096
  gemm_bt<__bf16><<<dim3(6144 / 128, S_LEN / 128), 256, 0, stream>>>(
      xb, wqkvb, qkv, DIM_, DIM_, DIM_, QKV_LD);

  // rope on Q + K parts
  rope_kernel<<<(S_LEN * 40 * 64) / 256, 256, 0, stream>>>(qkv, fc, fs);

  // causal GQA attention (256 blocks x 256 threads, balanced pairs)
  attn_kernel<<<256, 256, 0, stream>>>(qkv, attnO);

  // out = attnO @ wo^T : M=2048, N=4096, K=4096 (f32 output)
  gemm_bt<float><<<dim3(DIM_ / 128, S_LEN / 128), 256, 0, stream>>>(
      attnO, wob, out, DIM_, DIM_, DIM_, DIM_);
}

// Round 5
// 394.193 us; speedup vs baseline: 1.3176x; 1.0286x over previous
//
#include <hip/hip_runtime.h>
#include <hip/hip_bf16.h>
#include <cstdint>
#include <cstddef>

// ---------------------------------------------------------------------------
// Attention block: qkv = x @ wqkv^T ; rope(q,k) ; causal GQA attention ; out = att @ wo^T
// B=1, S=2048, DIM=4096, NH=32, NKV=8, HD=128. All compute in bf16 MFMA + f32 accum.
// ---------------------------------------------------------------------------

typedef __attribute__((ext_vector_type(4)))  float    f32x4;
typedef __attribute__((ext_vector_type(16))) float    f32x16;
typedef __attribute__((ext_vector_type(8)))  __bf16   bf16x8;
typedef __attribute__((ext_vector_type(4)))  __bf16   bf16x4;
typedef __attribute__((ext_vector_type(2)))  __bf16   bf16x2;
typedef __attribute__((ext_vector_type(4)))  uint32_t u32x4;

typedef const __attribute__((address_space(1))) void* gaddr_t;
typedef __attribute__((address_space(3))) void*       laddr_t;

#define S_LEN   2048
#define DIM_    4096
#define NH      32
#define NKV     8
#define HD      128
#define QKV_LD  6144   // row stride of qkv buffer (Q|K|V)
#define KOFF    4096
#define VOFF    5120

#define EXP2F(x) __builtin_amdgcn_exp2f(x)   // v_exp_f32 (2^x); __exp2f collides with glibc macro

// ---------------- f32 -> bf16 conversion (vectorized x4) -------------------
__global__ void cvt_f32_bf16(const float* __restrict__ in, __bf16* __restrict__ out, int n4) {
  int idx = blockIdx.x * blockDim.x + threadIdx.x;
  int stride = gridDim.x * blockDim.x;
  for (int i = idx; i < n4; i += stride) {
    float4 v = reinterpret_cast<const float4*>(in)[i];
    bf16x4 o;
    o[0] = (__bf16)v.x; o[1] = (__bf16)v.y; o[2] = (__bf16)v.z; o[3] = (__bf16)v.w;
    reinterpret_cast<bf16x4*>(out)[i] = o;
  }
}

// ---------------- RoPE in-place on Q and K parts of qkv --------------------
__global__ void rope_kernel(__bf16* __restrict__ qkv, const float* __restrict__ fc,
                            const float* __restrict__ fs) {
  int tid = blockIdx.x * 256 + threadIdx.x;   // 0 .. 2048*40*64-1
  int i = tid & 63;
  int t = tid >> 6;
  int h = t % 40;
  int s = t / 40;
  int col = (h < NH) ? (h * HD + 2 * i) : (KOFF + (h - NH) * HD + 2 * i);
  size_t off = (size_t)s * QKV_LD + col;
  float c = fc[s * 64 + i], sn = fs[s * 64 + i];
  bf16x2 v = *reinterpret_cast<bf16x2*>(&qkv[off]);
  float t0 = (float)v[0], t1 = (float)v[1];
  bf16x2 o;
  o[0] = (__bf16)(t0 * c - t1 * sn);
  o[1] = (__bf16)(t0 * sn + t1 * c);
  *reinterpret_cast<bf16x2*>(&qkv[off]) = o;
}

// ---------------- 8-phase 256-wide GEMM: C = A[M,K] * B[N,K]^T -------------
// 512 thr = 8 waves (2Mx4N). BK=64, double-buffered LDS (A: BM x 64, B: 256 x 64
// per buf), XOR-swizzled 16B groups (byte ^= (row&7)<<4) staged via inverse-
// swizzled global source (global_load_lds, linear dest). Per phase: 12 (or 8)
// ds_read_b128 + staging -> raw barrier -> lgkmcnt(0) -> 16 (or 8) MFMA ->
// barrier. vmcnt(0) only at phases 4/8; stage issues front-loaded (phases 1-2)
// so loads are >=2 phases old at the wait.
__device__ __forceinline__ void stage128(const __bf16* __restrict__ P, int ld, int row0,
                                         int kt, char* dst, int tid) {
#pragma unroll
  for (int j = 0; j < 2; ++j) {
    int c = j * 512 + tid;                 // 16B chunk: row r, col-group g
    int r = c >> 3, g = c & 7;
    const __bf16* src = P + (size_t)(row0 + r) * ld + kt * 64 + ((g ^ (r & 7)) * 8);
    __builtin_amdgcn_global_load_lds((gaddr_t)src,
        (laddr_t)(dst + j * 8192 + (tid & ~63) * 16), 16, 0, 0);
  }
}

template <int BM, int Q, bool DOVM>
__device__ __forceinline__ void gphase(const __bf16* Ab, const __bf16* Bb,
                                       f32x4 (&acc)[BM / 32][4],
                                       int wm, int wn, int l15, int hi4, int tid,
                                       bool s0, bool s1, const __bf16* __restrict__ P, int ld,
                                       int row0a, char* dsta, int row0b, char* dstb, int kt) {
  constexpr int MFR = BM / 64;             // m-frags per phase
  constexpr int QM = Q >> 1, QN = Q & 1;
  bf16x8 af[MFR][2], bf_[2][2];
#pragma unroll
  for (int mi = 0; mi < MFR; ++mi) {
    int R = wm * (BM / 2) + QM * (BM / 4) + mi * 16 + l15;
#pragma unroll
    for (int kk = 0; kk < 2; ++kk)
      af[mi][kk] = *reinterpret_cast<const bf16x8*>(
          (const char*)Ab + R * 128 + (((kk * 4 + hi4) ^ (R & 7)) * 16));
  }
#pragma unroll
  for (int ni = 0; ni < 2; ++ni) {
    int R = wn * 64 + QN * 32 + ni * 16 + l15;
#pragma unroll
    for (int kk = 0; kk < 2; ++kk)
      bf_[ni][kk] = *reinterpret_cast<const bf16x8*>(
          (const char*)Bb + R * 128 + (((kk * 4 + hi4) ^ (R & 7)) * 16));
  }
  if (s0) stage128(P, ld, row0a, kt, dsta, tid);
  if (s1) stage128(P, ld, row0b, kt, dstb, tid);
  __builtin_amdgcn_s_barrier();
  asm volatile("s_waitcnt lgkmcnt(0)" ::: "memory");
  __builtin_amdgcn_sched_barrier(0);
  __builtin_amdgcn_s_setprio(1);
#pragma unroll
  for (int mi = 0; mi < MFR; ++mi)
#pragma unroll
    for (int ni = 0; ni < 2; ++ni)
#pragma unroll
      for (int kk = 0; kk < 2; ++kk)
        acc[QM * MFR + mi][QN * 2 + ni] = __builtin_amdgcn_mfma_f32_16x16x32_bf16(
            af[mi][kk], bf_[ni][kk], acc[QM * MFR + mi][QN * 2 + ni], 0, 0, 0);
  __builtin_amdgcn_s_setprio(0);
  if (DOVM) asm volatile("s_waitcnt vmcnt(0)" ::: "memory");
  __builtin_amdgcn_s_barrier();
}

template <int BM, typename OutT>
__global__ __launch_bounds__(512, 2) void gemm_bt8(const __bf16* __restrict__ A,
                                                   const __bf16* __restrict__ B,
                                                   OutT* __restrict__ C, int K,
                                                   int lda, int ldb, int ldc, int nbx) {
  __shared__ __align__(16) __bf16 As[2][BM * 64];
  __shared__ __align__(16) __bf16 Bs[2][256 * 64];
  const int tid = threadIdx.x;
  const int l15 = tid & 15, hi4 = (tid >> 4) & 3, w = tid >> 6;
  const int wm = w >> 2, wn = w & 3;
  // XCD row-panel swizzle (gridDim.x % 8 == 0, blocks-per-XCD % nbx == 0)
  const int cpx = gridDim.x >> 3;
  const int id2 = ((int)blockIdx.x & 7) * cpx + ((int)blockIdx.x >> 3);
  const int m0 = (id2 / nbx) * BM, n0 = (id2 % nbx) * 256;

  f32x4 acc[BM / 32][4] = {};

  // prologue: stage tile 0 into buf0
  stage128(A, lda, m0, 0, (char*)As[0], tid);
  if constexpr (BM == 256) stage128(A, lda, m0 + 128, 0, (char*)As[0] + 16384, tid);
  stage128(B, ldb, n0, 0, (char*)Bs[0], tid);
  stage128(B, ldb, n0 + 128, 0, (char*)Bs[0] + 16384, tid);
  asm volatile("s_waitcnt vmcnt(0)" ::: "memory");
  __builtin_amdgcn_s_barrier();

  const int ntiles = K >> 6;               // 64-wide K-tiles (even count)
  for (int it = 0; it < ntiles; it += 2) {
    const int t1 = it + 1, t2 = it + 2;
    const bool more = t2 < ntiles;
    // phases 1-4: compute tile it from buf0; stage tile t1 -> buf1 (A in p1, B in p2)
    gphase<BM, 0, false>(As[0], Bs[0], acc, wm, wn, l15, hi4, tid,
                         true, BM == 256, A, lda, m0, (char*)As[1], m0 + 128, (char*)As[1] + 16384, t1);
    gphase<BM, 1, false>(As[0], Bs[0], acc, wm, wn, l15, hi4, tid,
                         true, true, B, ldb, n0, (char*)Bs[1], n0 + 128, (char*)Bs[1] + 16384, t1);
    gphase<BM, 2, false>(As[0], Bs[0], acc, wm, wn, l15, hi4, tid,
                         false, false, A, lda, 0, (char*)As[1], 0, (char*)As[1], t1);
    gphase<BM, 3, true >(As[0], Bs[0], acc, wm, wn, l15, hi4, tid,
                         false, false, A, lda, 0, (char*)As[1], 0, (char*)As[1], t1);
    // phases 5-8: compute tile t1 from buf1; stage tile t2 -> buf0
    gphase<BM, 0, false>(As[1], Bs[1], acc, wm, wn, l15, hi4, tid,
                         more, more && BM == 256, A, lda, m0, (char*)As[0], m0 + 128, (char*)As[0] + 16384, t2);
    gphase<BM, 1, false>(As[1], Bs[1], acc, wm, wn, l15, hi4, tid,
                         more, more, B, ldb, n0, (char*)Bs[0], n0 + 128, (char*)Bs[0] + 16384, t2);
    gphase<BM, 2, false>(As[1], Bs[1], acc, wm, wn, l15, hi4, tid,
                         false, false, A, lda, 0, (char*)As[0], 0, (char*)As[0], t2);
    gphase<BM, 3, true >(As[1], Bs[1], acc, wm, wn, l15, hi4, tid,
                         false, false, A, lda, 0, (char*)As[0], 0, (char*)As[0], t2);
  }

#pragma unroll
  for (int MI = 0; MI < BM / 32; ++MI)
#pragma unroll
    for (int NI = 0; NI < 4; ++NI)
#pragma unroll
      for (int j = 0; j < 4; ++j) {
        int row = m0 + wm * (BM / 2) + MI * 16 + hi4 * 4 + j;
        int col = n0 + wn * 64 + NI * 16 + l15;
        C[(size_t)row * ldc + col] = (OutT)acc[MI][NI][j];
      }
}

// ---------------- Flash attention, causal, GQA — balanced + pipelined ------
// 256 blocks x 256 thr (4 waves x 32 q-rows = QBLK 128). Block = (head, pair):
// processes q-tiles qt=pr and qt=15-pr sequentially -> EVERY block = 34
// kv-tile iterations (perfect balance, 1 block/CU). K and V^T double-buffered;
// one barrier per tile; staging for t+1 issued at top of t (latency hidden).
__device__ inline uint32_t pack2(float a, float b) {
  bf16x2 t; t[0] = (__bf16)a; t[1] = (__bf16)b;
  return __builtin_bit_cast(uint32_t, t);
}

__global__ __launch_bounds__(256, 2) void attn_kernel(const __bf16* __restrict__ qkv,
                                                      __bf16* __restrict__ out) {
  __shared__ __align__(16) __bf16 Ks[2][64 * 128];   // XOR-swizzled 16B groups
  __shared__ __align__(16) __bf16 Vt[2][128][72];    // V^T, padded (stride 144B)
  const int tid = threadIdx.x;
  const int lane = tid & 63, l31 = lane & 31, hi = lane >> 5, wq = tid >> 6;
  const int head = blockIdx.x & 31;
  const int pr = blockIdx.x >> 5;                    // 0..7
  const int kvh = head >> 2;
  const float sc2 = 0.08838834764831845f * 1.44269504089f;  // 1/sqrt(128)*log2(e)

  bf16x8 vr[2][2];  // in-flight V rows (2 tasks x 2 rows)

  auto stage_k = [&](int tt, int buf) {
#pragma unroll
    for (int i = 0; i < 4; ++i) {
      int c = i * 256 + tid;                         // 16B chunk 0..1023
      int r = c >> 4, g = c & 15;
      const __bf16* gk = qkv + (size_t)(tt * 64 + r) * QKV_LD + KOFF + kvh * HD + ((g ^ (r & 7)) * 8);
      __builtin_amdgcn_global_load_lds((gaddr_t)gk,
          (laddr_t)((char*)Ks[buf] + (tid & ~63) * 16 + i * 4096), 16, 0, 0);
    }
  };
  auto load_v = [&](int tt) {
#pragma unroll
    for (int i = 0; i < 2; ++i) {
      int task = i * 256 + tid;                      // 0..511
      int p = task >> 4, cg = task & 15;
      const __bf16* vp = qkv + (size_t)(tt * 64 + 2 * p) * QKV_LD + VOFF + kvh * HD + cg * 8;
      vr[i][0] = *reinterpret_cast<const bf16x8*>(vp);
      vr[i][1] = *reinterpret_cast<const bf16x8*>(vp + QKV_LD);
    }
  };
  auto write_v = [&](int buf) {
#pragma unroll
    for (int i = 0; i < 2; ++i) {
      int task = i * 256 + tid;
      int p = task >> 4, cg = task & 15;
#pragma unroll
      for (int e0 = 0; e0 < 8; ++e0) {
        int e = e0 ^ (lane & 7);
        bf16x2 pkv; pkv[0] = vr[i][0][e]; pkv[1] = vr[i][1][e];
        *reinterpret_cast<bf16x2*>(&Vt[buf][cg * 8 + e][2 * p]) = pkv;
      }
    }
  };

  for (int pass = 0; pass < 2; ++pass) {
    const int qt = pass ? (15 - pr) : pr;
    const int q0 = qt * 128;
    const int nt = 2 * qt + 2;                       // kv tiles (causal)
    const int qr = q0 + wq * 32 + l31;               // this lane's q row

    // Q fragments (B-layout): lane holds Q[qr][k = ks*16 + hi*8 + 0..7]
    bf16x8 qf[8];
    {
      const __bf16* qp = qkv + (size_t)qr * QKV_LD + head * HD + hi * 8;
#pragma unroll
      for (int ks = 0; ks < 8; ++ks) qf[ks] = *reinterpret_cast<const bf16x8*>(qp + ks * 16);
    }
    f32x16 o[4] = {};
    float m_run = -3e38f, l_run = 0.f;

    __syncthreads();          // prev pass epilogue LDS reads done (no-op cost pass 0)
    stage_k(0, 0); load_v(0); write_v(0);

    for (int t = 0; t < nt; ++t) {
      const int cur = t & 1;
      __syncthreads();        // staging of buf[cur] visible; prev reads of buf[1-cur] done
      if (t + 1 < nt) { stage_k(t + 1, 1 - cur); load_v(t + 1); }

      // ---- S^T = K Q^T : col=q=l31, row=(e&3)+8*(e>>2)+4*hi
      f32x16 st[2];
#pragma unroll
      for (int sub = 0; sub < 2; ++sub) {
        f32x16 acc = {};
        int r = sub * 32 + l31;
#pragma unroll
        for (int ks = 0; ks < 8; ++ks) {
          int g = (ks * 2 + hi) ^ (r & 7);
          bf16x8 kf = *reinterpret_cast<const bf16x8*>((char*)Ks[cur] + r * 256 + g * 16);
          acc = __builtin_amdgcn_mfma_f32_32x32x16_bf16(kf, qf[ks], acc, 0, 0, 0);
        }
        st[sub] = acc;
      }
#pragma unroll
      for (int sub = 0; sub < 2; ++sub)
#pragma unroll
        for (int e = 0; e < 16; ++e) st[sub][e] *= sc2;
      if (t >= nt - 2) {      // only the two diagonal tiles need masking
        const int kv0 = t * 64;
#pragma unroll
        for (int sub = 0; sub < 2; ++sub)
#pragma unroll
          for (int e = 0; e < 16; ++e) {
            int kvg = kv0 + sub * 32 + (e & 3) + 8 * (e >> 2) + 4 * hi;
            if (kvg > qr) st[sub][e] = -1e30f;
          }
      }
      // ---- online softmax (lane-local, defer-max)
      float pm = st[0][0];
#pragma unroll
      for (int e = 1; e < 16; ++e) pm = fmaxf(pm, st[0][e]);
#pragma unroll
      for (int e = 0; e < 16; ++e) pm = fmaxf(pm, st[1][e]);
      pm = fmaxf(pm, __shfl_xor(pm, 32));
      if (!__all(pm - m_run <= 8.f)) {
        float mn = fmaxf(m_run, pm);
        float fsc = EXP2F(m_run - mn);
        m_run = mn;
        l_run *= fsc;
#pragma unroll
        for (int dt = 0; dt < 4; ++dt)
#pragma unroll
          for (int e = 0; e < 16; ++e) o[dt][e] *= fsc;
      }
      float rs = 0.f;
#pragma unroll
      for (int sub = 0; sub < 2; ++sub)
#pragma unroll
        for (int e = 0; e < 16; ++e) {
          float p = EXP2F(st[sub][e] - m_run);
          st[sub][e] = p;
          rs += p;
        }
      rs += __shfl_xor(rs, 32);
      l_run += rs;

      // ---- pack P to bf16 B-fragments: pf[tt] = P[qr][kv = tt*16 + hi*8 + 0..7]
      uint32_t pk[16];
#pragma unroll
      for (int sub = 0; sub < 2; ++sub)
#pragma unroll
        for (int i = 0; i < 8; ++i)
          pk[sub * 8 + i] = pack2(st[sub][2 * i], st[sub][2 * i + 1]);
      uint32_t rv[8];
#pragma unroll
      for (int m = 0; m < 8; ++m) {
        int base = 4 * (m >> 1) + (m & 1);
        uint32_t snd = hi ? pk[base] : pk[base + 2];
        rv[m] = __shfl_xor(snd, 32);
      }
      bf16x8 pf[4];
#pragma unroll
      for (int tt = 0; tt < 4; ++tt) {
        u32x4 w;
        w[0] = hi ? rv[2 * tt]     : pk[4 * tt];
        w[1] = hi ? rv[2 * tt + 1] : pk[4 * tt + 1];
        w[2] = hi ? pk[4 * tt + 2] : rv[2 * tt];
        w[3] = hi ? pk[4 * tt + 3] : rv[2 * tt + 1];
        pf[tt] = __builtin_bit_cast(bf16x8, w);
      }
      // ---- O^T += V^T P^T
#pragma unroll
      for (int dt = 0; dt < 4; ++dt) {
        int dr = dt * 32 + l31;
#pragma unroll
        for (int tt = 0; tt < 4; ++tt) {
          bf16x8 vf = *reinterpret_cast<const bf16x8*>((char*)&Vt[cur][0][0] + dr * 144 + tt * 32 + hi * 16);
          o[dt] = __builtin_amdgcn_mfma_f32_32x32x16_bf16(vf, pf[tt], o[dt], 0, 0, 0);
        }
      }
      // ---- late V^T write for next tile (loads had QK+softmax+PV to land)
      if (t + 1 < nt) write_v(1 - cur);
    }

    // ---- epilogue: transpose O^T -> O via per-wave LDS scratch, coalesced stores
    float inv = 1.f / l_run;
    __bf16* scr = &Ks[0][0] + wq * 1280;             // [32][40] bf16 per wave
    const int qq = lane >> 1, part = lane & 1;
#pragma unroll
    for (int dt = 0; dt < 4; ++dt) {
      __syncthreads();                               // all waves done reading Ks/Vt (or prev dt)
#pragma unroll
      for (int i = 0; i < 8; ++i) {
        int d0 = (2 * i & 3) + 8 * (i >> 1) + 4 * hi;
        bf16x2 prr;
        prr[0] = (__bf16)(o[dt][2 * i] * inv);
        prr[1] = (__bf16)(o[dt][2 * i + 1] * inv);
        *reinterpret_cast<bf16x2*>(scr + l31 * 40 + d0) = prr;
      }
      __syncthreads();
      bf16x8 r0 = *reinterpret_cast<const bf16x8*>(scr + qq * 40 + part * 16);
      bf16x8 r1 = *reinterpret_cast<const bf16x8*>(scr + qq * 40 + part * 16 + 8);
      __bf16* op = out + (size_t)(q0 + wq * 32 + qq) * DIM_ + head * HD + dt * 32 + part * 16;
      *reinterpret_cast<bf16x8*>(op) = r0;
      *reinterpret_cast<bf16x8*>(op + 8) = r1;
    }
  }
}

// ---------------------------------------------------------------------------
extern "C" void kernel_launch(void* const* d_in, const int* in_sizes, int n_in,
                              void* d_out, int out_size, void* d_ws, size_t ws_size,
                              hipStream_t stream) {
  (void)in_sizes; (void)n_in; (void)out_size; (void)ws_size;
  const float* x    = (const float*)d_in[0];
  const float* fc   = (const float*)d_in[1];
  const float* fs   = (const float*)d_in[2];
  // d_in[3] = mask (causal, hardcoded in attn_kernel)
  const float* wqkv = (const float*)d_in[4];
  const float* wo   = (const float*)d_in[5];
  float* out = (float*)d_out;

  char* ws = (char*)d_ws;
  __bf16* xb    = (__bf16*)(ws);                       // 16,777,216  (reused as attn_out)
  __bf16* wqkvb = (__bf16*)(ws + 16777216);            // 50,331,648
  __bf16* wob   = (__bf16*)(ws + 67108864);            // 33,554,432
  __bf16* qkv   = (__bf16*)(ws + 100663296);           // 25,165,824
  __bf16* attnO = xb;                                  // xb dead after gemm1

  cvt_f32_bf16<<<2048, 256, 0, stream>>>(x,    xb,    (S_LEN * DIM_) / 4);
  cvt_f32_bf16<<<2048, 256, 0, stream>>>(wqkv, wqkvb, (6144 * DIM_) / 4);
  cvt_f32_bf16<<<2048, 256, 0, stream>>>(wo,   wob,   (DIM_ * DIM_) / 4);

  // qkv = x @ wqkv^T : M=2048, N=6144, K=4096 (256x256 tiles, 192 blocks)
  gemm_bt8<256, __bf16><<<192, 512, 0, stream>>>(xb, wqkvb, qkv, DIM_, DIM_, DIM_, QKV_LD, 24);

  // rope on Q + K parts
  rope_kernel<<<(S_LEN * 40 * 64) / 256, 256, 0, stream>>>(qkv, fc, fs);

  // causal GQA attention (256 blocks x 256 threads, balanced pairs)
  attn_kernel<<<256, 256, 0, stream>>>(qkv, attnO);

  // out = attnO @ wo^T : M=2048, N=4096, K=4096 (128x256 tiles, 256 blocks, f32 out)
  gemm_bt8<128, float><<<256, 512, 0, stream>>>(attnO, wob, out, DIM_, DIM_, DIM_, DIM_, 16);
}

// Round 6
// 383.612 us; speedup vs baseline: 1.3539x; 1.0276x over previous
//
#include <hip/hip_runtime.h>
#include <hip/hip_bf16.h>
#include <cstdint>
#include <cstddef>

// ---------------------------------------------------------------------------
// Attention block: qkv = x @ wqkv^T ; rope(q,k) ; causal GQA attention ; out = att @ wo^T
// B=1, S=2048, DIM=4096, NH=32, NKV=8, HD=128. All compute in bf16 MFMA + f32 accum.
// ---------------------------------------------------------------------------

typedef __attribute__((ext_vector_type(4)))  float    f32x4;
typedef __attribute__((ext_vector_type(16))) float    f32x16;
typedef __attribute__((ext_vector_type(8)))  __bf16   bf16x8;
typedef __attribute__((ext_vector_type(4)))  __bf16   bf16x4;
typedef __attribute__((ext_vector_type(2)))  __bf16   bf16x2;
typedef __attribute__((ext_vector_type(4)))  uint32_t u32x4;

typedef const __attribute__((address_space(1))) void* gaddr_t;
typedef __attribute__((address_space(3))) void*       laddr_t;

#define S_LEN   2048
#define DIM_    4096
#define NH      32
#define NKV     8
#define HD      128
#define QKV_LD  6144   // row stride of qkv buffer (Q|K|V)
#define KOFF    4096
#define VOFF    5120

#define EXP2F(x) __builtin_amdgcn_exp2f(x)   // v_exp_f32 (2^x); __exp2f collides with glibc macro

// ---------------- f32 -> bf16 conversion (vectorized x4) -------------------
__global__ void cvt_f32_bf16(const float* __restrict__ in, __bf16* __restrict__ out, int n4) {
  int idx = blockIdx.x * blockDim.x + threadIdx.x;
  int stride = gridDim.x * blockDim.x;
  for (int i = idx; i < n4; i += stride) {
    float4 v = reinterpret_cast<const float4*>(in)[i];
    bf16x4 o;
    o[0] = (__bf16)v.x; o[1] = (__bf16)v.y; o[2] = (__bf16)v.z; o[3] = (__bf16)v.w;
    reinterpret_cast<bf16x4*>(out)[i] = o;
  }
}

// ---------------- RoPE in-place on Q and K parts of qkv --------------------
__global__ void rope_kernel(__bf16* __restrict__ qkv, const float* __restrict__ fc,
                            const float* __restrict__ fs) {
  int tid = blockIdx.x * 256 + threadIdx.x;   // 0 .. 2048*40*64-1
  int i = tid & 63;
  int t = tid >> 6;
  int h = t % 40;
  int s = t / 40;
  int col = (h < NH) ? (h * HD + 2 * i) : (KOFF + (h - NH) * HD + 2 * i);
  size_t off = (size_t)s * QKV_LD + col;
  float c = fc[s * 64 + i], sn = fs[s * 64 + i];
  bf16x2 v = *reinterpret_cast<bf16x2*>(&qkv[off]);
  float t0 = (float)v[0], t1 = (float)v[1];
  bf16x2 o;
  o[0] = (__bf16)(t0 * c - t1 * sn);
  o[1] = (__bf16)(t0 * sn + t1 * c);
  *reinterpret_cast<bf16x2*>(&qkv[off]) = o;
}

// ---------------- 8-phase GEMM: C[M,N] = A[M,K] * B[N,K]^T -----------------
// 512 thr = 8 waves (2M x 4N). BK=64, double-buffered XOR-swizzled LDS.
// Per K-tile: 4 phases (QM,QK quadrants), each {ds_read frags | staging ->
// s_barrier -> lgkmcnt(0) -> sched_barrier -> setprio(1) MFMA setprio(0) ->
// [vmcnt(0) last phase] -> s_barrier}. Tile t+1's stages all issued at phase 1
// of tile t (~3 phases of cover); XCD-chunked grid keeps loads L2-resident.
__device__ __forceinline__ void stage64(const __bf16* __restrict__ P, int ld, int row0,
                                        int kt, char* dst, int tid) {
  int r = tid >> 3, g = tid & 7;           // 64 rows x 8 col-groups of 16B
  const __bf16* src = P + (size_t)(row0 + r) * ld + kt * 64 + ((g ^ (r & 7)) * 8);
  __builtin_amdgcn_global_load_lds((gaddr_t)src,
      (laddr_t)(dst + (tid & ~63) * 16), 16, 0, 0);
}

template <int BM, int BN, int QM, int QK, bool ST, bool VM>
__device__ __forceinline__ void phase8(const __bf16* Ab, const __bf16* Bb,
                                       f32x4 (&acc)[BM / 32][BN / 64],
                                       int wm, int wn, int l15, int hi4, int tid,
                                       const __bf16* __restrict__ A, int lda, int m0, char* dA,
                                       const __bf16* __restrict__ B, int ldb, int n0, char* dB,
                                       int kt) {
  constexpr int MH = BM / 64;              // m-frags per phase
  constexpr int NI = BN / 64;              // n-frags per wave
  bf16x8 af[MH], bfr[NI];
#pragma unroll
  for (int mi = 0; mi < MH; ++mi) {
    int R = wm * (BM / 2) + QM * (BM / 4) + mi * 16 + l15;
    af[mi] = *reinterpret_cast<const bf16x8*>(
        (const char*)Ab + R * 128 + (((QK * 4 + hi4) ^ (R & 7)) * 16));
  }
#pragma unroll
  for (int ni = 0; ni < NI; ++ni) {
    int R = wn * (BN / 4) + ni * 16 + l15;
    bfr[ni] = *reinterpret_cast<const bf16x8*>(
        (const char*)Bb + R * 128 + (((QK * 4 + hi4) ^ (R & 7)) * 16));
  }
  if (ST) {
#pragma unroll
    for (int h = 0; h < BM / 64; ++h) stage64(A, lda, m0 + h * 64, kt, dA + h * 8192, tid);
#pragma unroll
    for (int h = 0; h < BN / 64; ++h) stage64(B, ldb, n0 + h * 64, kt, dB + h * 8192, tid);
  }
  __builtin_amdgcn_s_barrier();
  asm volatile("s_waitcnt lgkmcnt(0)" ::: "memory");
  __builtin_amdgcn_sched_barrier(0);
  __builtin_amdgcn_s_setprio(1);
#pragma unroll
  for (int mi = 0; mi < MH; ++mi)
#pragma unroll
    for (int ni = 0; ni < NI; ++ni)
      acc[QM * MH + mi][ni] = __builtin_amdgcn_mfma_f32_16x16x32_bf16(
          af[mi], bfr[ni], acc[QM * MH + mi][ni], 0, 0, 0);
  __builtin_amdgcn_s_setprio(0);
  if (VM) asm volatile("s_waitcnt vmcnt(0)" ::: "memory");
  __builtin_amdgcn_s_barrier();
}

// sx/mxn: XCD chunk decomposition (chunk = 4 block-rows x 8 block-cols).
template <int BM, int BN, typename OutT>
__global__ __launch_bounds__(512, 2) void gemm8(const __bf16* __restrict__ A,
                                                const __bf16* __restrict__ B,
                                                OutT* __restrict__ C, int K,
                                                int lda, int ldb, int ldc,
                                                int sx, int mxn) {
  constexpr int ASZ = BM * 64, BSZ = BN * 64;
  __shared__ __align__(16) __bf16 As[2][ASZ];
  __shared__ __align__(16) __bf16 Bs[2][BSZ];
  const int tid = threadIdx.x;
  const int l15 = tid & 15, hi4 = (tid >> 4) & 3, w = tid >> 6;
  const int wm = w >> 2, wn = w & 3;
  const int bid = blockIdx.x, xcd = bid & 7, lid = bid >> 3;
  const int cm = (xcd >> sx) * 4 + (lid >> 3);
  const int cn = (xcd & mxn) * 8 + (lid & 7);
  const int m0 = cm * BM, n0 = cn * BN;

  f32x4 acc[BM / 32][BN / 64] = {};

  // prologue: stage tile 0 -> buf0
#pragma unroll
  for (int h = 0; h < BM / 64; ++h) stage64(A, lda, m0 + h * 64, 0, (char*)As[0] + h * 8192, tid);
#pragma unroll
  for (int h = 0; h < BN / 64; ++h) stage64(B, ldb, n0 + h * 64, 0, (char*)Bs[0] + h * 8192, tid);
  asm volatile("s_waitcnt vmcnt(0)" ::: "memory");
  __builtin_amdgcn_s_barrier();

  const int ntiles = K >> 6;
  for (int t = 0; t < ntiles; ++t) {
    const int cur = t & 1;
    const __bf16* Ab = As[cur];
    const __bf16* Bb = Bs[cur];
    char* dA = (char*)As[1 - cur];
    char* dB = (char*)Bs[1 - cur];
    if (t + 1 < ntiles)
      phase8<BM, BN, 0, 0, true,  false>(Ab, Bb, acc, wm, wn, l15, hi4, tid, A, lda, m0, dA, B, ldb, n0, dB, t + 1);
    else
      phase8<BM, BN, 0, 0, false, false>(Ab, Bb, acc, wm, wn, l15, hi4, tid, A, lda, m0, dA, B, ldb, n0, dB, 0);
    phase8<BM, BN, 0, 1, false, false>(Ab, Bb, acc, wm, wn, l15, hi4, tid, A, lda, m0, dA, B, ldb, n0, dB, 0);
    phase8<BM, BN, 1, 0, false, false>(Ab, Bb, acc, wm, wn, l15, hi4, tid, A, lda, m0, dA, B, ldb, n0, dB, 0);
    phase8<BM, BN, 1, 1, false, true >(Ab, Bb, acc, wm, wn, l15, hi4, tid, A, lda, m0, dA, B, ldb, n0, dB, 0);
  }

#pragma unroll
  for (int MI = 0; MI < BM / 32; ++MI)
#pragma unroll
    for (int NI = 0; NI < BN / 64; ++NI)
#pragma unroll
      for (int j = 0; j < 4; ++j) {
        int row = m0 + wm * (BM / 2) + MI * 16 + hi4 * 4 + j;
        int col = n0 + wn * (BN / 4) + NI * 16 + l15;
        C[(size_t)row * ldc + col] = (OutT)acc[MI][NI][j];
      }
}

// ---------------- Flash attention, causal, GQA — balanced + pipelined ------
// 256 blocks x 256 thr (4 waves x 32 q-rows = QBLK 128). Block = (head, pair):
// processes q-tiles qt=pr and qt=15-pr sequentially -> EVERY block = 34
// kv-tile iterations (perfect balance, 1 block/CU). K and V^T double-buffered;
// one barrier per tile; staging for t+1 issued at top of t (latency hidden).
__device__ inline uint32_t pack2(float a, float b) {
  bf16x2 t; t[0] = (__bf16)a; t[1] = (__bf16)b;
  return __builtin_bit_cast(uint32_t, t);
}

__global__ __launch_bounds__(256, 2) void attn_kernel(const __bf16* __restrict__ qkv,
                                                      __bf16* __restrict__ out) {
  __shared__ __align__(16) __bf16 Ks[2][64 * 128];   // XOR-swizzled 16B groups
  __shared__ __align__(16) __bf16 Vt[2][128][72];    // V^T, padded (stride 144B)
  const int tid = threadIdx.x;
  const int lane = tid & 63, l31 = lane & 31, hi = lane >> 5, wq = tid >> 6;
  const int head = blockIdx.x & 31;
  const int pr = blockIdx.x >> 5;                    // 0..7
  const int kvh = head >> 2;
  const float sc2 = 0.08838834764831845f * 1.44269504089f;  // 1/sqrt(128)*log2(e)

  bf16x8 vr[2][2];  // in-flight V rows (2 tasks x 2 rows)

  auto stage_k = [&](int tt, int buf) {
#pragma unroll
    for (int i = 0; i < 4; ++i) {
      int c = i * 256 + tid;                         // 16B chunk 0..1023
      int r = c >> 4, g = c & 15;
      const __bf16* gk = qkv + (size_t)(tt * 64 + r) * QKV_LD + KOFF + kvh * HD + ((g ^ (r & 7)) * 8);
      __builtin_amdgcn_global_load_lds((gaddr_t)gk,
          (laddr_t)((char*)Ks[buf] + (tid & ~63) * 16 + i * 4096), 16, 0, 0);
    }
  };
  auto load_v = [&](int tt) {
#pragma unroll
    for (int i = 0; i < 2; ++i) {
      int task = i * 256 + tid;                      // 0..511
      int p = task >> 4, cg = task & 15;
      const __bf16* vp = qkv + (size_t)(tt * 64 + 2 * p) * QKV_LD + VOFF + kvh * HD + cg * 8;
      vr[i][0] = *reinterpret_cast<const bf16x8*>(vp);
      vr[i][1] = *reinterpret_cast<const bf16x8*>(vp + QKV_LD);
    }
  };
  auto write_v = [&](int buf) {
#pragma unroll
    for (int i = 0; i < 2; ++i) {
      int task = i * 256 + tid;
      int p = task >> 4, cg = task & 15;
#pragma unroll
      for (int e0 = 0; e0 < 8; ++e0) {
        int e = e0 ^ (lane & 7);
        bf16x2 pkv; pkv[0] = vr[i][0][e]; pkv[1] = vr[i][1][e];
        *reinterpret_cast<bf16x2*>(&Vt[buf][cg * 8 + e][2 * p]) = pkv;
      }
    }
  };

  for (int pass = 0; pass < 2; ++pass) {
    const int qt = pass ? (15 - pr) : pr;
    const int q0 = qt * 128;
    const int nt = 2 * qt + 2;                       // kv tiles (causal)
    const int qr = q0 + wq * 32 + l31;               // this lane's q row

    // Q fragments (B-layout): lane holds Q[qr][k = ks*16 + hi*8 + 0..7]
    bf16x8 qf[8];
    {
      const __bf16* qp = qkv + (size_t)qr * QKV_LD + head * HD + hi * 8;
#pragma unroll
      for (int ks = 0; ks < 8; ++ks) qf[ks] = *reinterpret_cast<const bf16x8*>(qp + ks * 16);
    }
    f32x16 o[4] = {};
    float m_run = -3e38f, l_run = 0.f;

    __syncthreads();          // prev pass epilogue LDS reads done (no-op cost pass 0)
    stage_k(0, 0); load_v(0); write_v(0);

    for (int t = 0; t < nt; ++t) {
      const int cur = t & 1;
      __syncthreads();        // staging of buf[cur] visible; prev reads of buf[1-cur] done
      if (t + 1 < nt) { stage_k(t + 1, 1 - cur); load_v(t + 1); }

      // ---- S^T = K Q^T : col=q=l31, row=(e&3)+8*(e>>2)+4*hi
      f32x16 st[2];
#pragma unroll
      for (int sub = 0; sub < 2; ++sub) {
        f32x16 acc = {};
        int r = sub * 32 + l31;
#pragma unroll
        for (int ks = 0; ks < 8; ++ks) {
          int g = (ks * 2 + hi) ^ (r & 7);
          bf16x8 kf = *reinterpret_cast<const bf16x8*>((char*)Ks[cur] + r * 256 + g * 16);
          acc = __builtin_amdgcn_mfma_f32_32x32x16_bf16(kf, qf[ks], acc, 0, 0, 0);
        }
        st[sub] = acc;
      }
#pragma unroll
      for (int sub = 0; sub < 2; ++sub)
#pragma unroll
        for (int e = 0; e < 16; ++e) st[sub][e] *= sc2;
      if (t >= nt - 2) {      // only the two diagonal tiles need masking
        const int kv0 = t * 64;
#pragma unroll
        for (int sub = 0; sub < 2; ++sub)
#pragma unroll
          for (int e = 0; e < 16; ++e) {
            int kvg = kv0 + sub * 32 + (e & 3) + 8 * (e >> 2) + 4 * hi;
            if (kvg > qr) st[sub][e] = -1e30f;
          }
      }
      // ---- online softmax (lane-local, defer-max)
      float pm = st[0][0];
#pragma unroll
      for (int e = 1; e < 16; ++e) pm = fmaxf(pm, st[0][e]);
#pragma unroll
      for (int e = 0; e < 16; ++e) pm = fmaxf(pm, st[1][e]);
      pm = fmaxf(pm, __shfl_xor(pm, 32));
      if (!__all(pm - m_run <= 8.f)) {
        float mn = fmaxf(m_run, pm);
        float fsc = EXP2F(m_run - mn);
        m_run = mn;
        l_run *= fsc;
#pragma unroll
        for (int dt = 0; dt < 4; ++dt)
#pragma unroll
          for (int e = 0; e < 16; ++e) o[dt][e] *= fsc;
      }
      float rs = 0.f;
#pragma unroll
      for (int sub = 0; sub < 2; ++sub)
#pragma unroll
        for (int e = 0; e < 16; ++e) {
          float p = EXP2F(st[sub][e] - m_run);
          st[sub][e] = p;
          rs += p;
        }
      rs += __shfl_xor(rs, 32);
      l_run += rs;

      // ---- pack P to bf16 B-fragments: pf[tt] = P[qr][kv = tt*16 + hi*8 + 0..7]
      uint32_t pk[16];
#pragma unroll
      for (int sub = 0; sub < 2; ++sub)
#pragma unroll
        for (int i = 0; i < 8; ++i)
          pk[sub * 8 + i] = pack2(st[sub][2 * i], st[sub][2 * i + 1]);
      uint32_t rv[8];
#pragma unroll
      for (int m = 0; m < 8; ++m) {
        int base = 4 * (m >> 1) + (m & 1);
        uint32_t snd = hi ? pk[base] : pk[base + 2];
        rv[m] = __shfl_xor(snd, 32);
      }
      bf16x8 pf[4];
#pragma unroll
      for (int tt = 0; tt < 4; ++tt) {
        u32x4 w;
        w[0] = hi ? rv[2 * tt]     : pk[4 * tt];
        w[1] = hi ? rv[2 * tt + 1] : pk[4 * tt + 1];
        w[2] = hi ? pk[4 * tt + 2] : rv[2 * tt];
        w[3] = hi ? pk[4 * tt + 3] : rv[2 * tt + 1];
        pf[tt] = __builtin_bit_cast(bf16x8, w);
      }
      // ---- O^T += V^T P^T
#pragma unroll
      for (int dt = 0; dt < 4; ++dt) {
        int dr = dt * 32 + l31;
#pragma unroll
        for (int tt = 0; tt < 4; ++tt) {
          bf16x8 vf = *reinterpret_cast<const bf16x8*>((char*)&Vt[cur][0][0] + dr * 144 + tt * 32 + hi * 16);
          o[dt] = __builtin_amdgcn_mfma_f32_32x32x16_bf16(vf, pf[tt], o[dt], 0, 0, 0);
        }
      }
      // ---- late V^T write for next tile (loads had QK+softmax+PV to land)
      if (t + 1 < nt) write_v(1 - cur);
    }

    // ---- epilogue: transpose O^T -> O via per-wave LDS scratch, coalesced stores
    float inv = 1.f / l_run;
    __bf16* scr = &Ks[0][0] + wq * 1280;             // [32][40] bf16 per wave
    const int qq = lane >> 1, part = lane & 1;
#pragma unroll
    for (int dt = 0; dt < 4; ++dt) {
      __syncthreads();                               // all waves done reading Ks/Vt (or prev dt)
#pragma unroll
      for (int i = 0; i < 8; ++i) {
        int d0 = (2 * i & 3) + 8 * (i >> 1) + 4 * hi;
        bf16x2 prr;
        prr[0] = (__bf16)(o[dt][2 * i] * inv);
        prr[1] = (__bf16)(o[dt][2 * i + 1] * inv);
        *reinterpret_cast<bf16x2*>(scr + l31 * 40 + d0) = prr;
      }
      __syncthreads();
      bf16x8 r0 = *reinterpret_cast<const bf16x8*>(scr + qq * 40 + part * 16);
      bf16x8 r1 = *reinterpret_cast<const bf16x8*>(scr + qq * 40 + part * 16 + 8);
      __bf16* op = out + (size_t)(q0 + wq * 32 + qq) * DIM_ + head * HD + dt * 32 + part * 16;
      *reinterpret_cast<bf16x8*>(op) = r0;
      *reinterpret_cast<bf16x8*>(op + 8) = r1;
    }
  }
}

// ---------------------------------------------------------------------------
extern "C" void kernel_launch(void* const* d_in, const int* in_sizes, int n_in,
                              void* d_out, int out_size, void* d_ws, size_t ws_size,
                              hipStream_t stream) {
  (void)in_sizes; (void)n_in; (void)out_size; (void)ws_size;
  const float* x    = (const float*)d_in[0];
  const float* fc   = (const float*)d_in[1];
  const float* fs   = (const float*)d_in[2];
  // d_in[3] = mask (causal, hardcoded in attn_kernel)
  const float* wqkv = (const float*)d_in[4];
  const float* wo   = (const float*)d_in[5];
  float* out = (float*)d_out;

  char* ws = (char*)d_ws;
  __bf16* xb    = (__bf16*)(ws);                       // 16,777,216  (reused as attn_out)
  __bf16* wqkvb = (__bf16*)(ws + 16777216);            // 50,331,648
  __bf16* wob   = (__bf16*)(ws + 67108864);            // 33,554,432
  __bf16* qkv   = (__bf16*)(ws + 100663296);           // 25,165,824
  __bf16* attnO = xb;                                  // xb dead after gemm1

  cvt_f32_bf16<<<2048, 256, 0, stream>>>(x,    xb,    (S_LEN * DIM_) / 4);
  cvt_f32_bf16<<<2048, 256, 0, stream>>>(wqkv, wqkvb, (6144 * DIM_) / 4);
  cvt_f32_bf16<<<2048, 256, 0, stream>>>(wo,   wob,   (DIM_ * DIM_) / 4);

  // qkv = x @ wqkv^T : M=2048, N=6144, K=4096. 256x192 tiles -> 8x32 = 256 blocks.
  // XCD chunk 4Mx8N: cm=(xcd>>2)*4+(lid>>3), cn=(xcd&3)*8+(lid&7)  (sx=2, mxn=3)
  gemm8<256, 192, __bf16><<<256, 512, 0, stream>>>(xb, wqkvb, qkv, DIM_, DIM_, DIM_, QKV_LD, 2, 3);

  // rope on Q + K parts
  rope_kernel<<<(S_LEN * 40 * 64) / 256, 256, 0, stream>>>(qkv, fc, fs);

  // causal GQA attention (256 blocks x 256 threads, balanced pairs)
  attn_kernel<<<256, 256, 0, stream>>>(qkv, attnO);

  // out = attnO @ wo^T : M=2048, N=4096, K=4096. 128x256 tiles -> 16x16 = 256 blocks.
  // XCD chunk 4Mx8N: cm=(xcd>>1)*4+(lid>>3), cn=(xcd&1)*8+(lid&7)  (sx=1, mxn=1)
  gemm8<128, 256, float><<<256, 512, 0, stream>>>(attnO, wob, out, DIM_, DIM_, DIM_, DIM_, 1, 1);
}

// Round 8
// 369.675 us; speedup vs baseline: 1.4050x; 1.0377x over previous
//
#include <hip/hip_runtime.h>
#include <hip/hip_bf16.h>
#include <cstdint>
#include <cstddef>

// ---------------------------------------------------------------------------
// Attention block: qkv = x @ wqkv^T ; rope(q,k) ; causal GQA attention ; out = att @ wo^T
// B=1, S=2048, DIM=4096, NH=32, NKV=8, HD=128. All compute in bf16 MFMA + f32 accum.
// ---------------------------------------------------------------------------

typedef __attribute__((ext_vector_type(4)))  float    f32x4;
typedef __attribute__((ext_vector_type(16))) float    f32x16;
typedef __attribute__((ext_vector_type(8)))  __bf16   bf16x8;
typedef __attribute__((ext_vector_type(4)))  __bf16   bf16x4;
typedef __attribute__((ext_vector_type(2)))  __bf16   bf16x2;
typedef __attribute__((ext_vector_type(4)))  uint32_t u32x4;

typedef const __attribute__((address_space(1))) void* gaddr_t;
typedef __attribute__((address_space(3))) void*       laddr_t;

#define S_LEN   2048
#define DIM_    4096
#define NHEADS  32
#define NKV     8
#define HD      128
#define QKV_LD  6144   // row stride of qkv buffer (Q|K|V)
#define KOFF    4096
#define VOFF    5120

#define EXP2F(x) __builtin_amdgcn_exp2f(x)   // v_exp_f32 (2^x); __exp2f collides with glibc macro

// ---------------- f32 -> bf16 conversion (vectorized x4) -------------------
__global__ void cvt_f32_bf16(const float* __restrict__ in, __bf16* __restrict__ out, int n4) {
  int idx = blockIdx.x * blockDim.x + threadIdx.x;
  int stride = gridDim.x * blockDim.x;
  for (int i = idx; i < n4; i += stride) {
    float4 v = reinterpret_cast<const float4*>(in)[i];
    bf16x4 o;
    o[0] = (__bf16)v.x; o[1] = (__bf16)v.y; o[2] = (__bf16)v.z; o[3] = (__bf16)v.w;
    reinterpret_cast<bf16x4*>(out)[i] = o;
  }
}

// ---------------- RoPE in-place on Q and K parts of qkv --------------------
__global__ void rope_kernel(__bf16* __restrict__ qkv, const float* __restrict__ fc,
                            const float* __restrict__ fs) {
  int tid = blockIdx.x * 256 + threadIdx.x;   // 0 .. 2048*40*64-1
  int i = tid & 63;
  int t = tid >> 6;
  int h = t % 40;
  int s = t / 40;
  int col = (h < NHEADS) ? (h * HD + 2 * i) : (KOFF + (h - NHEADS) * HD + 2 * i);
  size_t off = (size_t)s * QKV_LD + col;
  float c = fc[s * 64 + i], sn = fs[s * 64 + i];
  bf16x2 v = *reinterpret_cast<bf16x2*>(&qkv[off]);
  float t0 = (float)v[0], t1 = (float)v[1];
  bf16x2 o;
  o[0] = (__bf16)(t0 * c - t1 * sn);
  o[1] = (__bf16)(t0 * sn + t1 * c);
  *reinterpret_cast<bf16x2*>(&qkv[off]) = o;
}

// ---------------- 32x32-MFMA GEMM: C[M,N] = A[M,K] * B[N,K]^T --------------
// 512 thr = 8 waves (2M x 4N); per-wave 128x64 (BM=256) or 64x64 (BM=128) via
// mfma_f32_32x32x16_bf16 (2x FLOPs per LDS fragment byte vs 16x16x32).
// BK=64, double-buffered XOR-swizzled LDS (byte ^= (row&7)<<4), staged via
// inverse-swizzled global source. 2 phases per K-tile (k-half), each:
// {frag ds_reads | staging gloads -> s_barrier -> lgkmcnt(0) -> sched_barrier
//  -> setprio(1) MFMA setprio(0) -> [vmcnt(0) phase 2] -> s_barrier}.
__device__ __forceinline__ void stage64(const __bf16* __restrict__ P, int ld, int row0,
                                        int kt, char* dst, int tid) {
  int r = tid >> 3, g = tid & 7;           // 64 rows x 8 col-groups of 16B
  const __bf16* src = P + (size_t)(row0 + r) * ld + kt * 64 + ((g ^ (r & 7)) * 8);
  __builtin_amdgcn_global_load_lds((gaddr_t)src,
      (laddr_t)(dst + (tid & ~63) * 16), 16, 0, 0);
}

template <int MW, int NW, int KH, int NST, bool VM>
__device__ __forceinline__ void phase32(const __bf16* __restrict__ Ab,
                                        const __bf16* __restrict__ Bb,
                                        f32x16 (&acc)[MW][NW],
                                        int wm, int wn, int l31, int hi, int tid,
                                        const __bf16* __restrict__ SP, int sld,
                                        int srow0, char* sdst, int kt, bool st) {
  bf16x8 af[MW][2], bfr[NW][2];
#pragma unroll
  for (int mi = 0; mi < MW; ++mi) {
    int R = wm * (MW * 32) + mi * 32 + l31;
#pragma unroll
    for (int k2 = 0; k2 < 2; ++k2)
      af[mi][k2] = *reinterpret_cast<const bf16x8*>(
          (const char*)Ab + R * 128 + (((KH * 4 + k2 * 2 + hi) ^ (R & 7)) * 16));
  }
#pragma unroll
  for (int ni = 0; ni < NW; ++ni) {
    int R = wn * (NW * 32) + ni * 32 + l31;
#pragma unroll
    for (int k2 = 0; k2 < 2; ++k2)
      bfr[ni][k2] = *reinterpret_cast<const bf16x8*>(
          (const char*)Bb + R * 128 + (((KH * 4 + k2 * 2 + hi) ^ (R & 7)) * 16));
  }
  if (st) {
#pragma unroll
    for (int h = 0; h < NST; ++h)
      stage64(SP, sld, srow0 + h * 64, kt, sdst + h * 8192, tid);
  }
  __builtin_amdgcn_s_barrier();
  asm volatile("s_waitcnt lgkmcnt(0)" ::: "memory");
  __builtin_amdgcn_sched_barrier(0);
  __builtin_amdgcn_s_setprio(1);
#pragma unroll
  for (int k2 = 0; k2 < 2; ++k2)
#pragma unroll
    for (int mi = 0; mi < MW; ++mi)
#pragma unroll
      for (int ni = 0; ni < NW; ++ni)
        acc[mi][ni] = __builtin_amdgcn_mfma_f32_32x32x16_bf16(af[mi][k2], bfr[ni][k2],
                                                              acc[mi][ni], 0, 0, 0);
  __builtin_amdgcn_s_setprio(0);
  if (VM) asm volatile("s_waitcnt vmcnt(0)" ::: "memory");
  __builtin_amdgcn_s_barrier();
}

// Grid: bid -> xcd = bid&7 (round-robin dispatch), lid = bid>>3.
// m-block = lid % MB ; n-block = xcd * NPX + lid / MB  (per-XCD chunk: MB x NPX).
template <int BM, int BN, int MB, int NPX, typename OutT>
__global__ __launch_bounds__(512, 1) void gemm32(const __bf16* __restrict__ A,
                                                 const __bf16* __restrict__ B,
                                                 OutT* __restrict__ C, int K,
                                                 int lda, int ldb, int ldc) {
  constexpr int MW = BM / 64;    // per-wave M frags (wave spans BM/2 rows)
  constexpr int NW = BN / 128;   // per-wave N frags (wave spans BN/4 cols)
  constexpr int AST = BM / 64, BST = BN / 64;
  __shared__ __align__(16) __bf16 As[2][BM * 64];
  __shared__ __align__(16) __bf16 Bs[2][BN * 64];
  const int tid = threadIdx.x;
  const int lane = tid & 63, l31 = lane & 31, hi = lane >> 5, w = tid >> 6;
  const int wm = w >> 2, wn = w & 3;
  const int bid = blockIdx.x, xcd = bid & 7, lid = bid >> 3;
  const int m0 = (lid % MB) * BM;
  const int n0 = (xcd * NPX + lid / MB) * BN;

  f32x16 acc[MW][NW] = {};

  // prologue: stage tile 0 -> buf0
#pragma unroll
  for (int h = 0; h < AST; ++h) stage64(A, lda, m0 + h * 64, 0, (char*)As[0] + h * 8192, tid);
#pragma unroll
  for (int h = 0; h < BST; ++h) stage64(B, ldb, n0 + h * 64, 0, (char*)Bs[0] + h * 8192, tid);
  asm volatile("s_waitcnt vmcnt(0)" ::: "memory");
  __builtin_amdgcn_s_barrier();

  const int ntiles = K >> 6;
  for (int t = 0; t < ntiles; ++t) {
    const int cur = t & 1;
    const __bf16* Ab = As[cur];
    const __bf16* Bb = Bs[cur];
    char* dA = (char*)As[1 - cur];
    char* dB = (char*)Bs[1 - cur];
    const bool st = (t + 1 < ntiles);
    // phase 1 (k 0..31): stage next A ; phase 2 (k 32..63): stage next B, drain
    phase32<MW, NW, 0, AST, false>(Ab, Bb, acc, wm, wn, l31, hi, tid,
                                   A, lda, m0, dA, t + 1, st);
    phase32<MW, NW, 1, BST, true >(Ab, Bb, acc, wm, wn, l31, hi, tid,
                                   B, ldb, n0, dB, t + 1, st);
  }

  // epilogue: D col = l31 (n), row = (e&3) + 8*(e>>2) + 4*hi (m)
#pragma unroll
  for (int mi = 0; mi < MW; ++mi)
#pragma unroll
    for (int ni = 0; ni < NW; ++ni)
#pragma unroll
      for (int e = 0; e < 16; ++e) {
        int row = m0 + wm * (MW * 32) + mi * 32 + (e & 3) + 8 * (e >> 2) + 4 * hi;
        int col = n0 + wn * (NW * 32) + ni * 32 + l31;
        C[(size_t)row * ldc + col] = (OutT)acc[mi][ni][e];
      }
}

// ---------------- Flash attention, causal, GQA — balanced + pipelined ------
// 256 blocks x 256 thr (4 waves x 32 q-rows = QBLK 128). Block = (head, pair):
// processes q-tiles qt=pr and qt=15-pr sequentially -> EVERY block = 34
// kv-tile iterations (perfect balance, 1 block/CU). K and V^T double-buffered;
// one barrier per tile; staging for t+1 issued at top of t (latency hidden).
__device__ inline uint32_t pack2(float a, float b) {
  bf16x2 t; t[0] = (__bf16)a; t[1] = (__bf16)b;
  return __builtin_bit_cast(uint32_t, t);
}

__global__ __launch_bounds__(256, 2) void attn_kernel(const __bf16* __restrict__ qkv,
                                                      __bf16* __restrict__ out) {
  __shared__ __align__(16) __bf16 Ks[2][64 * 128];   // XOR-swizzled 16B groups
  __shared__ __align__(16) __bf16 Vt[2][128][72];    // V^T, padded (stride 144B)
  const int tid = threadIdx.x;
  const int lane = tid & 63, l31 = lane & 31, hi = lane >> 5, wq = tid >> 6;
  const int head = blockIdx.x & 31;
  const int pr = blockIdx.x >> 5;                    // 0..7
  const int kvh = head >> 2;
  const float sc2 = 0.08838834764831845f * 1.44269504089f;  // 1/sqrt(128)*log2(e)

  bf16x8 vr[2][2];  // in-flight V rows (2 tasks x 2 rows)

  auto stage_k = [&](int tt, int buf) {
#pragma unroll
    for (int i = 0; i < 4; ++i) {
      int c = i * 256 + tid;                         // 16B chunk 0..1023
      int r = c >> 4, g = c & 15;
      const __bf16* gk = qkv + (size_t)(tt * 64 + r) * QKV_LD + KOFF + kvh * HD + ((g ^ (r & 7)) * 8);
      __builtin_amdgcn_global_load_lds((gaddr_t)gk,
          (laddr_t)((char*)Ks[buf] + (tid & ~63) * 16 + i * 4096), 16, 0, 0);
    }
  };
  auto load_v = [&](int tt) {
#pragma unroll
    for (int i = 0; i < 2; ++i) {
      int task = i * 256 + tid;                      // 0..511
      int p = task >> 4, cg = task & 15;
      const __bf16* vp = qkv + (size_t)(tt * 64 + 2 * p) * QKV_LD + VOFF + kvh * HD + cg * 8;
      vr[i][0] = *reinterpret_cast<const bf16x8*>(vp);
      vr[i][1] = *reinterpret_cast<const bf16x8*>(vp + QKV_LD);
    }
  };
  auto write_v = [&](int buf) {
#pragma unroll
    for (int i = 0; i < 2; ++i) {
      int task = i * 256 + tid;
      int p = task >> 4, cg = task & 15;
#pragma unroll
      for (int e0 = 0; e0 < 8; ++e0) {
        int e = e0 ^ (lane & 7);
        bf16x2 pkv; pkv[0] = vr[i][0][e]; pkv[1] = vr[i][1][e];
        *reinterpret_cast<bf16x2*>(&Vt[buf][cg * 8 + e][2 * p]) = pkv;
      }
    }
  };

  for (int pass = 0; pass < 2; ++pass) {
    const int qt = pass ? (15 - pr) : pr;
    const int q0 = qt * 128;
    const int nt = 2 * qt + 2;                       // kv tiles (causal)
    const int qr = q0 + wq * 32 + l31;               // this lane's q row

    // Q fragments (B-layout): lane holds Q[qr][k = ks*16 + hi*8 + 0..7]
    bf16x8 qf[8];
    {
      const __bf16* qp = qkv + (size_t)qr * QKV_LD + head * HD + hi * 8;
#pragma unroll
      for (int ks = 0; ks < 8; ++ks) qf[ks] = *reinterpret_cast<const bf16x8*>(qp + ks * 16);
    }
    f32x16 o[4] = {};
    float m_run = -3e38f, l_run = 0.f;

    __syncthreads();          // prev pass epilogue LDS reads done (no-op cost pass 0)
    stage_k(0, 0); load_v(0); write_v(0);

    for (int t = 0; t < nt; ++t) {
      const int cur = t & 1;
      __syncthreads();        // staging of buf[cur] visible; prev reads of buf[1-cur] done
      if (t + 1 < nt) { stage_k(t + 1, 1 - cur); load_v(t + 1); }

      // ---- S^T = K Q^T : col=q=l31, row=(e&3)+8*(e>>2)+4*hi
      f32x16 st[2];
#pragma unroll
      for (int sub = 0; sub < 2; ++sub) {
        f32x16 acc = {};
        int r = sub * 32 + l31;
#pragma unroll
        for (int ks = 0; ks < 8; ++ks) {
          int g = (ks * 2 + hi) ^ (r & 7);
          bf16x8 kf = *reinterpret_cast<const bf16x8*>((char*)Ks[cur] + r * 256 + g * 16);
          acc = __builtin_amdgcn_mfma_f32_32x32x16_bf16(kf, qf[ks], acc, 0, 0, 0);
        }
        st[sub] = acc;
      }
#pragma unroll
      for (int sub = 0; sub < 2; ++sub)
#pragma unroll
        for (int e = 0; e < 16; ++e) st[sub][e] *= sc2;
      if (t >= nt - 2) {      // only the two diagonal tiles need masking
        const int kv0 = t * 64;
#pragma unroll
        for (int sub = 0; sub < 2; ++sub)
#pragma unroll
          for (int e = 0; e < 16; ++e) {
            int kvg = kv0 + sub * 32 + (e & 3) + 8 * (e >> 2) + 4 * hi;
            if (kvg > qr) st[sub][e] = -1e30f;
          }
      }
      // ---- online softmax (lane-local, defer-max)
      float pm = st[0][0];
#pragma unroll
      for (int e = 1; e < 16; ++e) pm = fmaxf(pm, st[0][e]);
#pragma unroll
      for (int e = 0; e < 16; ++e) pm = fmaxf(pm, st[1][e]);
      pm = fmaxf(pm, __shfl_xor(pm, 32));
      if (!__all(pm - m_run <= 8.f)) {
        float mn = fmaxf(m_run, pm);
        float fsc = EXP2F(m_run - mn);
        m_run = mn;
        l_run *= fsc;
#pragma unroll
        for (int dt = 0; dt < 4; ++dt)
#pragma unroll
          for (int e = 0; e < 16; ++e) o[dt][e] *= fsc;
      }
      float rs = 0.f;
#pragma unroll
      for (int sub = 0; sub < 2; ++sub)
#pragma unroll
        for (int e = 0; e < 16; ++e) {
          float p = EXP2F(st[sub][e] - m_run);
          st[sub][e] = p;
          rs += p;
        }
      rs += __shfl_xor(rs, 32);
      l_run += rs;

      // ---- pack P to bf16 B-fragments: pf[tt] = P[qr][kv = tt*16 + hi*8 + 0..7]
      uint32_t pk[16];
#pragma unroll
      for (int sub = 0; sub < 2; ++sub)
#pragma unroll
        for (int i = 0; i < 8; ++i)
          pk[sub * 8 + i] = pack2(st[sub][2 * i], st[sub][2 * i + 1]);
      uint32_t rv[8];
#pragma unroll
      for (int m = 0; m < 8; ++m) {
        int base = 4 * (m >> 1) + (m & 1);
        uint32_t snd = hi ? pk[base] : pk[base + 2];
        rv[m] = __shfl_xor(snd, 32);
      }
      bf16x8 pf[4];
#pragma unroll
      for (int tt = 0; tt < 4; ++tt) {
        u32x4 w;
        w[0] = hi ? rv[2 * tt]     : pk[4 * tt];
        w[1] = hi ? rv[2 * tt + 1] : pk[4 * tt + 1];
        w[2] = hi ? pk[4 * tt + 2] : rv[2 * tt];
        w[3] = hi ? pk[4 * tt + 3] : rv[2 * tt + 1];
        pf[tt] = __builtin_bit_cast(bf16x8, w);
      }
      // ---- O^T += V^T P^T
#pragma unroll
      for (int dt = 0; dt < 4; ++dt) {
        int dr = dt * 32 + l31;
#pragma unroll
        for (int tt = 0; tt < 4; ++tt) {
          bf16x8 vf = *reinterpret_cast<const bf16x8*>((char*)&Vt[cur][0][0] + dr * 144 + tt * 32 + hi * 16);
          o[dt] = __builtin_amdgcn_mfma_f32_32x32x16_bf16(vf, pf[tt], o[dt], 0, 0, 0);
        }
      }
      // ---- late V^T write for next tile (loads had QK+softmax+PV to land)
      if (t + 1 < nt) write_v(1 - cur);
    }

    // ---- epilogue: transpose O^T -> O via per-wave LDS scratch, coalesced stores
    float inv = 1.f / l_run;
    __bf16* scr = &Ks[0][0] + wq * 1280;             // [32][40] bf16 per wave
    const int qq = lane >> 1, part = lane & 1;
#pragma unroll
    for (int dt = 0; dt < 4; ++dt) {
      __syncthreads();                               // all waves done reading Ks/Vt (or prev dt)
#pragma unroll
      for (int i = 0; i < 8; ++i) {
        int d0 = (2 * i & 3) + 8 * (i >> 1) + 4 * hi;
        bf16x2 prr;
        prr[0] = (__bf16)(o[dt][2 * i] * inv);
        prr[1] = (__bf16)(o[dt][2 * i + 1] * inv);
        *reinterpret_cast<bf16x2*>(scr + l31 * 40 + d0) = prr;
      }
      __syncthreads();
      bf16x8 r0 = *reinterpret_cast<const bf16x8*>(scr + qq * 40 + part * 16);
      bf16x8 r1 = *reinterpret_cast<const bf16x8*>(scr + qq * 40 + part * 16 + 8);
      __bf16* op = out + (size_t)(q0 + wq * 32 + qq) * DIM_ + head * HD + dt * 32 + part * 16;
      *reinterpret_cast<bf16x8*>(op) = r0;
      *reinterpret_cast<bf16x8*>(op + 8) = r1;
    }
  }
}

// ---------------------------------------------------------------------------
extern "C" void kernel_launch(void* const* d_in, const int* in_sizes, int n_in,
                              void* d_out, int out_size, void* d_ws, size_t ws_size,
                              hipStream_t stream) {
  (void)in_sizes; (void)n_in; (void)out_size; (void)ws_size;
  const float* x    = (const float*)d_in[0];
  const float* fc   = (const float*)d_in[1];
  const float* fs   = (const float*)d_in[2];
  // d_in[3] = mask (causal, hardcoded in attn_kernel)
  const float* wqkv = (const float*)d_in[4];
  const float* wo   = (const float*)d_in[5];
  float* out = (float*)d_out;

  char* ws = (char*)d_ws;
  __bf16* xb    = (__bf16*)(ws);                       // 16,777,216  (reused as attn_out)
  __bf16* wqkvb = (__bf16*)(ws + 16777216);            // 50,331,648
  __bf16* wob   = (__bf16*)(ws + 67108864);            // 33,554,432
  __bf16* qkv   = (__bf16*)(ws + 100663296);           // 25,165,824
  __bf16* attnO = xb;                                  // xb dead after gemm1

  cvt_f32_bf16<<<2048, 256, 0, stream>>>(x,    xb,    (S_LEN * DIM_) / 4);
  cvt_f32_bf16<<<2048, 256, 0, stream>>>(wqkv, wqkvb, (6144 * DIM_) / 4);
  cvt_f32_bf16<<<2048, 256, 0, stream>>>(wo,   wob,   (DIM_ * DIM_) / 4);

  // qkv = x @ wqkv^T : M=2048, N=6144, K=4096. 256x256 tiles -> 8x24 = 192 blocks.
  // Per-XCD chunk 8M x 3N (m = lid%8, n = xcd*3 + lid/8).
  gemm32<256, 256, 8, 3, __bf16><<<192, 512, 0, stream>>>(xb, wqkvb, qkv, DIM_, DIM_, DIM_, QKV_LD);

  // rope on Q + K parts
  rope_kernel<<<(S_LEN * 40 * 64) / 256, 256, 0, stream>>>(qkv, fc, fs);

  // causal GQA attention (256 blocks x 256 threads, balanced pairs)
  attn_kernel<<<256, 256, 0, stream>>>(qkv, attnO);

  // out = attnO @ wo^T : M=2048, N=4096, K=4096. 128x256 tiles -> 16x16 = 256 blocks.
  // Per-XCD chunk 16M x 2N (m = lid%16, n = xcd*2 + lid/16).
  gemm32<128, 256, 16, 2, float><<<256, 512, 0, stream>>>(attnO, wob, out, DIM_, DIM_, DIM_, DIM_);
}